// Round 2
// baseline (9415.536 us; speedup 1.0000x reference)
//
#include <hip/hip_runtime.h>
#include <math.h>

#define NSENS 9
#define NEDGE 72
#define NPAIR 36
#define HDIM 128
#define HPAD 132          // padded row stride: rows land on distinct bank groups
#define NLAYER 4
#define FEPS 1e-8f

// ---------------- thread->tile mapping for NC=128 GEMMs ----------------
// 512 threads = 8 waves = 2 column-blocks (64 cols) x 4 row-groups.
// Within a wave: 16 lanes x 4 cols cover the col-block; 4 row-subgroups.
// Each wave loads only its 64-col half of W (halves L1/L2 weight traffic).
struct Map128 { int c, rslot, rg; };
__device__ __forceinline__ Map128 map128() {
    const int tid = threadIdx.x;
    const int wave = tid >> 6, lane = tid & 63;
    Map128 m;
    m.rg    = wave >> 1;
    m.c     = (wave & 1) * 64 + (lane & 15) * 4;
    m.rslot = m.rg * 4 + (lane >> 4);   // 0..15, row r = rslot + i*16
    return m;
}

#define FMA4(A, s, W) do { (A).x = fmaf((s),(W).x,(A).x); (A).y = fmaf((s),(W).y,(A).y); \
                           (A).z = fmaf((s),(W).z,(A).z); (A).w = fmaf((s),(W).w,(A).w); } while(0)
#define FMASTEP(A, V, W0, W1, W2, W3) do { FMA4(A,(V).x,W0); FMA4(A,(V).y,W1); \
                                           FMA4(A,(V).z,W2); FMA4(A,(V).w,W3); } while(0)

// Accumulate acc[NR] (+= fetch[R][KTOT] @ W[KTOT][128], this thread's 4 cols).
// Manual double-buffered weight pipeline: 8 k-values per iteration, two
// register banks, next tile issued before the dependent FMA group.
template<int KTOT, int R, typename F>
__device__ __forceinline__ void gemm_acc128(const float* __restrict__ W, F fetch, float4* acc)
{
    Map128 m = map128();
    if (m.rg * 4 >= R) return;               // wave-uniform early out
    constexpr int NR = (R + 15) / 16;
    const float* Wc = W + m.c;
    float4 a0 = *(const float4*)(Wc + 0*HDIM), a1 = *(const float4*)(Wc + 1*HDIM);
    float4 a2 = *(const float4*)(Wc + 2*HDIM), a3 = *(const float4*)(Wc + 3*HDIM);
    for (int kk = 0; kk < KTOT; kk += 8) {
        const float* Wb = Wc + (kk + 4) * HDIM;
        float4 b0 = *(const float4*)(Wb + 0*HDIM), b1 = *(const float4*)(Wb + 1*HDIM);
        float4 b2 = *(const float4*)(Wb + 2*HDIM), b3 = *(const float4*)(Wb + 3*HDIM);
#pragma unroll
        for (int i = 0; i < NR; ++i) {
            const int r = m.rslot + i * 16;
            if (r < R) { float4 v = fetch(i, r, kk); FMASTEP(acc[i], v, a0, a1, a2, a3); }
        }
        if (kk + 8 < KTOT) {
            const float* Wa = Wc + (kk + 8) * HDIM;
            a0 = *(const float4*)(Wa + 0*HDIM); a1 = *(const float4*)(Wa + 1*HDIM);
            a2 = *(const float4*)(Wa + 2*HDIM); a3 = *(const float4*)(Wa + 3*HDIM);
        }
#pragma unroll
        for (int i = 0; i < NR; ++i) {
            const int r = m.rslot + i * 16;
            if (r < R) { float4 v = fetch(i, r, kk + 4); FMASTEP(acc[i], v, b0, b1, b2, b3); }
        }
    }
}

template<int R, bool RELU, bool ACCUM>
__device__ __forceinline__ void gemm_fin128(const float* __restrict__ bias,
                                            const float4* acc, float* __restrict__ dst)
{
    Map128 m = map128();
    if (m.rg * 4 >= R) return;
    constexpr int NR = (R + 15) / 16;
    const float4 b = *(const float4*)(bias + m.c);
#pragma unroll
    for (int i = 0; i < NR; ++i) {
        const int r = m.rslot + i * 16;
        if (r < R) {
            float4 v = acc[i];
            v.x += b.x; v.y += b.y; v.z += b.z; v.w += b.w;
            if (RELU) { v.x = fmaxf(v.x,0.f); v.y = fmaxf(v.y,0.f);
                        v.z = fmaxf(v.z,0.f); v.w = fmaxf(v.w,0.f); }
            float4* p = (float4*)(dst + r * HPAD + m.c);
            if (ACCUM) { float4 o = *p; v.x += o.x; v.y += o.y; v.z += o.z; v.w += o.w; }
            *p = v;
        }
    }
}

// ---------------- NC=64 (decoder hidden) — simple mapping ----------------
template<int KTOT, int R, typename F>
__device__ __forceinline__ void gemm_acc64(const float* __restrict__ W, F fetch, float4* acc)
{
    const int tid = threadIdx.x;
    const int c = (tid & 15) * 4;
    const int rslot = tid >> 4;              // 0..31
    constexpr int NR = (R + 31) / 32;
    const float* Wc = W + c;
    float4 a0 = *(const float4*)(Wc + 0*64), a1 = *(const float4*)(Wc + 1*64);
    float4 a2 = *(const float4*)(Wc + 2*64), a3 = *(const float4*)(Wc + 3*64);
    for (int kk = 0; kk < KTOT; kk += 8) {
        const float* Wb = Wc + (kk + 4) * 64;
        float4 b0 = *(const float4*)(Wb + 0*64), b1 = *(const float4*)(Wb + 1*64);
        float4 b2 = *(const float4*)(Wb + 2*64), b3 = *(const float4*)(Wb + 3*64);
#pragma unroll
        for (int i = 0; i < NR; ++i) {
            const int r = rslot + i * 32;
            if (r < R) { float4 v = fetch(i, r, kk); FMASTEP(acc[i], v, a0, a1, a2, a3); }
        }
        if (kk + 8 < KTOT) {
            const float* Wa = Wc + (kk + 8) * 64;
            a0 = *(const float4*)(Wa + 0*64); a1 = *(const float4*)(Wa + 1*64);
            a2 = *(const float4*)(Wa + 2*64); a3 = *(const float4*)(Wa + 3*64);
        }
#pragma unroll
        for (int i = 0; i < NR; ++i) {
            const int r = rslot + i * 32;
            if (r < R) { float4 v = fetch(i, r, kk + 4); FMASTEP(acc[i], v, b0, b1, b2, b3); }
        }
    }
}

template<int R, bool RELU>
__device__ __forceinline__ void gemm_fin64(const float* __restrict__ bias,
                                           const float4* acc, float* __restrict__ dst, int stride)
{
    const int tid = threadIdx.x;
    const int c = (tid & 15) * 4;
    const int rslot = tid >> 4;
    constexpr int NR = (R + 31) / 32;
    const float4 b = *(const float4*)(bias + c);
#pragma unroll
    for (int i = 0; i < NR; ++i) {
        const int r = rslot + i * 32;
        if (r < R) {
            float4 v = acc[i];
            v.x += b.x; v.y += b.y; v.z += b.z; v.w += b.w;
            if (RELU) { v.x = fmaxf(v.x,0.f); v.y = fmaxf(v.y,0.f);
                        v.z = fmaxf(v.z,0.f); v.w = fmaxf(v.w,0.f); }
            *(float4*)(dst + r * stride + c) = v;
        }
    }
}

#define ZACC4(A, N) do { _Pragma("unroll") for (int _i = 0; _i < (N); ++_i) \
                         (A)[_i] = make_float4(0.f,0.f,0.f,0.f); } while(0)

// One block (512 thr) per graph; all activations LDS-resident (~64 KB -> 2 blocks/CU).
extern "C" __global__ void __launch_bounds__(512, 4)
gnn_fused(const float* __restrict__ x_nodes, const float* __restrict__ damage_locs,
          const float* __restrict__ enc_n_w, const float* __restrict__ enc_n_b,
          const float* __restrict__ enc_e_w1, const float* __restrict__ enc_e_b1,
          const float* __restrict__ enc_e_w2, const float* __restrict__ enc_e_b2,
          const float* __restrict__ edge_w1, const float* __restrict__ edge_b1,
          const float* __restrict__ edge_w2, const float* __restrict__ edge_b2,
          const float* __restrict__ node_w1, const float* __restrict__ node_b1,
          const float* __restrict__ node_w2, const float* __restrict__ node_b2,
          const float* __restrict__ dec_w1, const float* __restrict__ dec_b1,
          const float* __restrict__ dec_w2, const float* __restrict__ dec_b2,
          float* __restrict__ out)
{
    __shared__ __align__(16) float s_hn[NSENS * HPAD];
    __shared__ __align__(16) float s_he[NEDGE * HPAD];
    __shared__ __align__(16) float s_t[36 * HPAD];     // MLP hidden (36-row chunks)
    __shared__ __align__(16) float s_phys[NEDGE * 8];
    __shared__ __align__(16) float s_ew1[8 * HDIM];    // enc_e_w1 zero-padded K=6->8
    __shared__ __align__(16) float s_sum[HDIM];
    __shared__ float s_val[NEDGE];
    __shared__ float s_x[NSENS * 2];
    __shared__ float s_dmg[2];
    __shared__ int s_src[NEDGE], s_dst[NEDGE];

    const int g = blockIdx.x;
    const int tid = threadIdx.x;

    // ---- stage inputs / static edge tables ----
    if (tid < NSENS * 2) s_x[tid] = x_nodes[g * NSENS * 2 + tid];
    if (tid < 2)         s_dmg[tid] = damage_locs[g * 2 + tid];
    if (tid < NEDGE) {
        int p = tid >> 1;
        int i = 0, rem = p, cnt = 8;
        while (rem >= cnt) { rem -= cnt; --cnt; ++i; }
        int j = i + 1 + rem;
        s_src[tid] = (tid & 1) ? j : i;
        s_dst[tid] = (tid & 1) ? i : j;
    }
    for (int idx = tid; idx < 8 * HDIM; idx += 512)
        s_ew1[idx] = (idx < 6 * HDIM) ? enc_e_w1[idx] : 0.f;
    __syncthreads();

    // ---- node encoder + edge phys features ----
    for (int idx = tid; idx < NSENS * HDIM; idx += 512) {
        int n = idx >> 7, h = idx & 127;
        s_hn[n * HPAD + h] = fmaf(s_x[2*n], enc_n_w[h],
                             fmaf(s_x[2*n+1], enc_n_w[HDIM + h], enc_n_b[h]));
    }
    if (tid < NEDGE) {
        const int si = s_src[tid], di = s_dst[tid];
        const float sx = s_x[2*si], sy = s_x[2*si+1];
        const float dx = s_x[2*di], dy = s_x[2*di+1];
        const float gx = s_dmg[0],  gy = s_dmg[1];
        const float vx = sx - dx, vy = sy - dy;
        const float vv = vx*vx + vy*vy;
        const float elen = sqrtf(vv + FEPS);
        const float l2 = fmaxf(vv, FEPS);
        float t = ((gx - sx) * (dx - sx) + (gy - sy) * (dy - sy)) / l2;
        t = fminf(fmaxf(t, 0.f), 1.f);
        const float px = sx + t * (dx - sx), py = sy + t * (dy - sy);
        const float d_path = sqrtf((gx-px)*(gx-px) + (gy-py)*(gy-py) + FEPS);
        const float d_tx   = sqrtf((sx-gx)*(sx-gx) + (sy-gy)*(sy-gy) + FEPS);
        const float d_rx   = sqrtf((dx-gx)*(dx-gx) + (dy-gy)*(dy-gy) + FEPS);
        float* ph = s_phys + tid * 8;
        ph[0]=vx; ph[1]=vy; ph[2]=elen; ph[3]=d_path; ph[4]=d_tx; ph[5]=d_rx;
        ph[6]=0.f; ph[7]=0.f;
    }
    __syncthreads();

    // ---- edge encoder ----
    for (int c0 = 0; c0 < NEDGE; c0 += 36) {
        float4 acc[3]; ZACC4(acc, 3);
        auto fP = [&](int i, int r, int kk) -> float4 {
            return *(const float4*)(s_phys + (c0 + r) * 8 + kk);
        };
        gemm_acc128<8, 36>(s_ew1, fP, acc);
        gemm_fin128<36, true, false>(enc_e_b1, acc, s_t);
        __syncthreads();
        float4 ac2[3]; ZACC4(ac2, 3);
        auto fT = [&](int i, int r, int kk) -> float4 {
            return *(const float4*)(s_t + r * HPAD + kk);
        };
        gemm_acc128<HDIM, 36>(enc_e_w2, fT, ac2);
        gemm_fin128<36, false, false>(enc_e_b2, ac2, s_he + c0 * HPAD);
        __syncthreads();
    }

    // ---- message-passing layers ----
    for (int l = 0; l < NLAYER; ++l) {
        const float* ew1 = edge_w1 + l * 3 * HDIM * HDIM;
        const float* eb1 = edge_b1 + l * HDIM;
        const float* ew2 = edge_w2 + l * HDIM * HDIM;
        const float* eb2 = edge_b2 + l * HDIM;

        for (int c0 = 0; c0 < NEDGE; c0 += 36) {
            Map128 m = map128();
            int baseS[3], baseD[3];
#pragma unroll
            for (int i = 0; i < 3; ++i) {
                const int r = m.rslot + i * 16;
                const int e = c0 + ((r < 36) ? r : 0);
                baseS[i] = s_src[e] * HPAD;
                baseD[i] = s_dst[e] * HPAD;
            }
            float4 acc[3]; ZACC4(acc, 3);
            gemm_acc128<HDIM, 36>(ew1, [&](int i, int r, int kk) -> float4 {
                return *(const float4*)(s_hn + baseS[i] + kk); }, acc);
            gemm_acc128<HDIM, 36>(ew1 + HDIM * HDIM, [&](int i, int r, int kk) -> float4 {
                return *(const float4*)(s_hn + baseD[i] + kk); }, acc);
            gemm_acc128<HDIM, 36>(ew1 + 2 * HDIM * HDIM, [&](int i, int r, int kk) -> float4 {
                return *(const float4*)(s_he + (c0 + r) * HPAD + kk); }, acc);
            gemm_fin128<36, true, false>(eb1, acc, s_t);
            __syncthreads();
            float4 ac2[3]; ZACC4(ac2, 3);
            gemm_acc128<HDIM, 36>(ew2, [&](int i, int r, int kk) -> float4 {
                return *(const float4*)(s_t + r * HPAD + kk); }, ac2);
            gemm_fin128<36, false, true>(eb2, ac2, s_he + c0 * HPAD);   // residual add
            __syncthreads();
        }

        // node update: complete graph -> agg[n] = (sum - h_n[n]) / 8
        if (tid < HDIM) {
            float s = 0.f;
#pragma unroll
            for (int n = 0; n < NSENS; ++n) s += s_hn[n * HPAD + tid];
            s_sum[tid] = s;
        }
        __syncthreads();
        float4 an[1]; ZACC4(an, 1);
        gemm_acc128<HDIM, NSENS>(node_w1 + l * 2 * HDIM * HDIM,
            [&](int i, int r, int kk) -> float4 {
                return *(const float4*)(s_hn + r * HPAD + kk); }, an);
        gemm_acc128<HDIM, NSENS>(node_w1 + l * 2 * HDIM * HDIM + HDIM * HDIM,
            [&](int i, int r, int kk) -> float4 {
                float4 a = *(const float4*)(s_hn + r * HPAD + kk);
                float4 s = *(const float4*)(s_sum + kk);
                return make_float4((s.x-a.x)*0.125f, (s.y-a.y)*0.125f,
                                   (s.z-a.z)*0.125f, (s.w-a.w)*0.125f); }, an);
        gemm_fin128<NSENS, true, false>(node_b1 + l * HDIM, an, s_t);
        __syncthreads();
        float4 an2[1]; ZACC4(an2, 1);
        gemm_acc128<HDIM, NSENS>(node_w2 + l * HDIM * HDIM,
            [&](int i, int r, int kk) -> float4 {
                return *(const float4*)(s_t + r * HPAD + kk); }, an2);
        gemm_fin128<NSENS, false, true>(node_b2 + l * HDIM, an2, s_hn); // residual add
        __syncthreads();
    }

    // ---- decoder ----
    for (int c0 = 0; c0 < NEDGE; c0 += 36) {
        float4 ad[2]; ZACC4(ad, 2);
        gemm_acc64<HDIM, 36>(dec_w1, [&](int i, int r, int kk) -> float4 {
            return *(const float4*)(s_he + (c0 + r) * HPAD + kk); }, ad);
        gemm_fin64<36, true>(dec_b1, ad, s_t, 68);
        __syncthreads();
        if (tid < 36) {
            float a = dec_b2[0];
            const float* tt = s_t + tid * 68;
#pragma unroll
            for (int k = 0; k < 64; ++k) a = fmaf(tt[k], dec_w2[k], a);
            s_val[c0 + tid] = 1.f / (1.f + expf(-a));
        }
        __syncthreads();
    }
    if (tid < NPAIR)
        out[g * NPAIR + tid] = 0.5f * (s_val[2 * tid] + s_val[2 * tid + 1]);
}

extern "C" void kernel_launch(void* const* d_in, const int* in_sizes, int n_in,
                              void* d_out, int out_size, void* d_ws, size_t ws_size,
                              hipStream_t stream) {
    const float* x_nodes     = (const float*)d_in[0];
    const float* damage_locs = (const float*)d_in[1];
    const float* enc_n_w  = (const float*)d_in[2];
    const float* enc_n_b  = (const float*)d_in[3];
    const float* enc_e_w1 = (const float*)d_in[4];
    const float* enc_e_b1 = (const float*)d_in[5];
    const float* enc_e_w2 = (const float*)d_in[6];
    const float* enc_e_b2 = (const float*)d_in[7];
    const float* edge_w1  = (const float*)d_in[8];
    const float* edge_b1  = (const float*)d_in[9];
    const float* edge_w2  = (const float*)d_in[10];
    const float* edge_b2  = (const float*)d_in[11];
    const float* node_w1  = (const float*)d_in[12];
    const float* node_b1  = (const float*)d_in[13];
    const float* node_w2  = (const float*)d_in[14];
    const float* node_b2  = (const float*)d_in[15];
    const float* dec_w1   = (const float*)d_in[16];
    const float* dec_b1   = (const float*)d_in[17];
    const float* dec_w2   = (const float*)d_in[18];
    const float* dec_b2   = (const float*)d_in[19];
    float* out = (float*)d_out;

    const int ngraph = in_sizes[1] / 2;   // damage_locs is [B,2]
    hipLaunchKernelGGL(gnn_fused, dim3(ngraph), dim3(512), 0, stream,
                       x_nodes, damage_locs,
                       enc_n_w, enc_n_b, enc_e_w1, enc_e_b1, enc_e_w2, enc_e_b2,
                       edge_w1, edge_b1, edge_w2, edge_b2,
                       node_w1, node_b1, node_w2, node_b2,
                       dec_w1, dec_b1, dec_w2, dec_b2, out);
}

// Round 3
// 5451.695 us; speedup vs baseline: 1.7271x; 1.7271x over previous
//
#include <hip/hip_runtime.h>
#include <math.h>

#define NSENS 9
#define NEDGE 72
#define NPAIR 36
#define HDIM 128
#define HPAD 132          // padded row stride: rows land on distinct bank groups
#define NLAYER 4
#define FEPS 1e-8f

// ---------------- thread->tile mapping for NC=128 GEMMs ----------------
// 512 threads = 8 waves = 2 column-blocks (64 cols) x 4 row-groups.
// Within a wave: 16 lanes x 4 cols cover the col-block; 4 row-subgroups.
// Each wave loads only its 64-col half of W (halves L1/L2 weight traffic).
struct Map128 { int c, rslot, rg; };
__device__ __forceinline__ Map128 map128() {
    const int tid = threadIdx.x;
    const int wave = tid >> 6, lane = tid & 63;
    Map128 m;
    m.rg    = wave >> 1;
    m.c     = (wave & 1) * 64 + (lane & 15) * 4;
    m.rslot = m.rg * 4 + (lane >> 4);   // 0..15, row r = rslot + i*16
    return m;
}

#define FMA4(A, s, W) do { (A).x = fmaf((s),(W).x,(A).x); (A).y = fmaf((s),(W).y,(A).y); \
                           (A).z = fmaf((s),(W).z,(A).z); (A).w = fmaf((s),(W).w,(A).w); } while(0)
#define FMASTEP(A, V, W0, W1, W2, W3) do { FMA4(A,(V).x,W0); FMA4(A,(V).y,W1); \
                                           FMA4(A,(V).z,W2); FMA4(A,(V).w,W3); } while(0)

// Accumulate acc[NR] (+= fetch[R][KTOT] @ W[KTOT][128], this thread's 4 cols).
// Manual double-buffered weight pipeline: 8 k-values per iteration, two
// register banks, next tile issued before the dependent FMA group.
// Needs ~32 VGPRs of weight regs + acc: requires the >=128-VGPR budget
// granted by __launch_bounds__(512,2). (512,4) capped at 64 VGPR -> 2.1 GB
// of scratch spill traffic per dispatch (round-2 counters).
template<int KTOT, int R, typename F>
__device__ __forceinline__ void gemm_acc128(const float* __restrict__ W, F fetch, float4* acc)
{
    Map128 m = map128();
    if (m.rg * 4 >= R) return;               // wave-uniform early out
    constexpr int NR = (R + 15) / 16;
    const float* Wc = W + m.c;
    float4 a0 = *(const float4*)(Wc + 0*HDIM), a1 = *(const float4*)(Wc + 1*HDIM);
    float4 a2 = *(const float4*)(Wc + 2*HDIM), a3 = *(const float4*)(Wc + 3*HDIM);
    for (int kk = 0; kk < KTOT; kk += 8) {
        const float* Wb = Wc + (kk + 4) * HDIM;
        float4 b0 = *(const float4*)(Wb + 0*HDIM), b1 = *(const float4*)(Wb + 1*HDIM);
        float4 b2 = *(const float4*)(Wb + 2*HDIM), b3 = *(const float4*)(Wb + 3*HDIM);
#pragma unroll
        for (int i = 0; i < NR; ++i) {
            const int r = m.rslot + i * 16;
            if (r < R) { float4 v = fetch(i, r, kk); FMASTEP(acc[i], v, a0, a1, a2, a3); }
        }
        if (kk + 8 < KTOT) {
            const float* Wa = Wc + (kk + 8) * HDIM;
            a0 = *(const float4*)(Wa + 0*HDIM); a1 = *(const float4*)(Wa + 1*HDIM);
            a2 = *(const float4*)(Wa + 2*HDIM); a3 = *(const float4*)(Wa + 3*HDIM);
        }
#pragma unroll
        for (int i = 0; i < NR; ++i) {
            const int r = m.rslot + i * 16;
            if (r < R) { float4 v = fetch(i, r, kk + 4); FMASTEP(acc[i], v, b0, b1, b2, b3); }
        }
    }
}

template<int R, bool RELU, bool ACCUM>
__device__ __forceinline__ void gemm_fin128(const float* __restrict__ bias,
                                            const float4* acc, float* __restrict__ dst)
{
    Map128 m = map128();
    if (m.rg * 4 >= R) return;
    constexpr int NR = (R + 15) / 16;
    const float4 b = *(const float4*)(bias + m.c);
#pragma unroll
    for (int i = 0; i < NR; ++i) {
        const int r = m.rslot + i * 16;
        if (r < R) {
            float4 v = acc[i];
            v.x += b.x; v.y += b.y; v.z += b.z; v.w += b.w;
            if (RELU) { v.x = fmaxf(v.x,0.f); v.y = fmaxf(v.y,0.f);
                        v.z = fmaxf(v.z,0.f); v.w = fmaxf(v.w,0.f); }
            float4* p = (float4*)(dst + r * HPAD + m.c);
            if (ACCUM) { float4 o = *p; v.x += o.x; v.y += o.y; v.z += o.z; v.w += o.w; }
            *p = v;
        }
    }
}

// ---------------- NC=64 (decoder hidden) — simple mapping ----------------
template<int KTOT, int R, typename F>
__device__ __forceinline__ void gemm_acc64(const float* __restrict__ W, F fetch, float4* acc)
{
    const int tid = threadIdx.x;
    const int c = (tid & 15) * 4;
    const int rslot = tid >> 4;              // 0..31
    constexpr int NR = (R + 31) / 32;
    const float* Wc = W + c;
    float4 a0 = *(const float4*)(Wc + 0*64), a1 = *(const float4*)(Wc + 1*64);
    float4 a2 = *(const float4*)(Wc + 2*64), a3 = *(const float4*)(Wc + 3*64);
    for (int kk = 0; kk < KTOT; kk += 8) {
        const float* Wb = Wc + (kk + 4) * 64;
        float4 b0 = *(const float4*)(Wb + 0*64), b1 = *(const float4*)(Wb + 1*64);
        float4 b2 = *(const float4*)(Wb + 2*64), b3 = *(const float4*)(Wb + 3*64);
#pragma unroll
        for (int i = 0; i < NR; ++i) {
            const int r = rslot + i * 32;
            if (r < R) { float4 v = fetch(i, r, kk); FMASTEP(acc[i], v, a0, a1, a2, a3); }
        }
        if (kk + 8 < KTOT) {
            const float* Wa = Wc + (kk + 8) * 64;
            a0 = *(const float4*)(Wa + 0*64); a1 = *(const float4*)(Wa + 1*64);
            a2 = *(const float4*)(Wa + 2*64); a3 = *(const float4*)(Wa + 3*64);
        }
#pragma unroll
        for (int i = 0; i < NR; ++i) {
            const int r = rslot + i * 32;
            if (r < R) { float4 v = fetch(i, r, kk + 4); FMASTEP(acc[i], v, b0, b1, b2, b3); }
        }
    }
}

template<int R, bool RELU>
__device__ __forceinline__ void gemm_fin64(const float* __restrict__ bias,
                                           const float4* acc, float* __restrict__ dst, int stride)
{
    const int tid = threadIdx.x;
    const int c = (tid & 15) * 4;
    const int rslot = tid >> 4;
    constexpr int NR = (R + 31) / 32;
    const float4 b = *(const float4*)(bias + c);
#pragma unroll
    for (int i = 0; i < NR; ++i) {
        const int r = rslot + i * 32;
        if (r < R) {
            float4 v = acc[i];
            v.x += b.x; v.y += b.y; v.z += b.z; v.w += b.w;
            if (RELU) { v.x = fmaxf(v.x,0.f); v.y = fmaxf(v.y,0.f);
                        v.z = fmaxf(v.z,0.f); v.w = fmaxf(v.w,0.f); }
            *(float4*)(dst + r * stride + c) = v;
        }
    }
}

#define ZACC4(A, N) do { _Pragma("unroll") for (int _i = 0; _i < (N); ++_i) \
                         (A)[_i] = make_float4(0.f,0.f,0.f,0.f); } while(0)

// One block (512 thr) per graph; all activations LDS-resident (~68 KB -> 2 blocks/CU).
// launch_bounds (512,2): occupancy is LDS-limited at 2 blocks/CU anyway, so give
// the register allocator the full 128-VGPR budget (round 2's (512,4) forced 64
// VGPRs -> massive scratch spills, VALUBusy 22%).
extern "C" __global__ void __launch_bounds__(512, 2)
gnn_fused(const float* __restrict__ x_nodes, const float* __restrict__ damage_locs,
          const float* __restrict__ enc_n_w, const float* __restrict__ enc_n_b,
          const float* __restrict__ enc_e_w1, const float* __restrict__ enc_e_b1,
          const float* __restrict__ enc_e_w2, const float* __restrict__ enc_e_b2,
          const float* __restrict__ edge_w1, const float* __restrict__ edge_b1,
          const float* __restrict__ edge_w2, const float* __restrict__ edge_b2,
          const float* __restrict__ node_w1, const float* __restrict__ node_b1,
          const float* __restrict__ node_w2, const float* __restrict__ node_b2,
          const float* __restrict__ dec_w1, const float* __restrict__ dec_b1,
          const float* __restrict__ dec_w2, const float* __restrict__ dec_b2,
          float* __restrict__ out)
{
    __shared__ __align__(16) float s_hn[NSENS * HPAD];
    __shared__ __align__(16) float s_he[NEDGE * HPAD];
    __shared__ __align__(16) float s_t[36 * HPAD];     // MLP hidden (36-row chunks)
    __shared__ __align__(16) float s_phys[NEDGE * 8];
    __shared__ __align__(16) float s_ew1[8 * HDIM];    // enc_e_w1 zero-padded K=6->8
    __shared__ __align__(16) float s_sum[HDIM];
    __shared__ float s_val[NEDGE];
    __shared__ float s_x[NSENS * 2];
    __shared__ float s_dmg[2];
    __shared__ int s_src[NEDGE], s_dst[NEDGE];

    const int g = blockIdx.x;
    const int tid = threadIdx.x;

    // ---- stage inputs / static edge tables ----
    if (tid < NSENS * 2) s_x[tid] = x_nodes[g * NSENS * 2 + tid];
    if (tid < 2)         s_dmg[tid] = damage_locs[g * 2 + tid];
    if (tid < NEDGE) {
        int p = tid >> 1;
        int i = 0, rem = p, cnt = 8;
        while (rem >= cnt) { rem -= cnt; --cnt; ++i; }
        int j = i + 1 + rem;
        s_src[tid] = (tid & 1) ? j : i;
        s_dst[tid] = (tid & 1) ? i : j;
    }
    for (int idx = tid; idx < 8 * HDIM; idx += 512)
        s_ew1[idx] = (idx < 6 * HDIM) ? enc_e_w1[idx] : 0.f;
    __syncthreads();

    // ---- node encoder + edge phys features ----
    for (int idx = tid; idx < NSENS * HDIM; idx += 512) {
        int n = idx >> 7, h = idx & 127;
        s_hn[n * HPAD + h] = fmaf(s_x[2*n], enc_n_w[h],
                             fmaf(s_x[2*n+1], enc_n_w[HDIM + h], enc_n_b[h]));
    }
    if (tid < NEDGE) {
        const int si = s_src[tid], di = s_dst[tid];
        const float sx = s_x[2*si], sy = s_x[2*si+1];
        const float dx = s_x[2*di], dy = s_x[2*di+1];
        const float gx = s_dmg[0],  gy = s_dmg[1];
        const float vx = sx - dx, vy = sy - dy;
        const float vv = vx*vx + vy*vy;
        const float elen = sqrtf(vv + FEPS);
        const float l2 = fmaxf(vv, FEPS);
        float t = ((gx - sx) * (dx - sx) + (gy - sy) * (dy - sy)) / l2;
        t = fminf(fmaxf(t, 0.f), 1.f);
        const float px = sx + t * (dx - sx), py = sy + t * (dy - sy);
        const float d_path = sqrtf((gx-px)*(gx-px) + (gy-py)*(gy-py) + FEPS);
        const float d_tx   = sqrtf((sx-gx)*(sx-gx) + (sy-gy)*(sy-gy) + FEPS);
        const float d_rx   = sqrtf((dx-gx)*(dx-gx) + (dy-gy)*(dy-gy) + FEPS);
        float* ph = s_phys + tid * 8;
        ph[0]=vx; ph[1]=vy; ph[2]=elen; ph[3]=d_path; ph[4]=d_tx; ph[5]=d_rx;
        ph[6]=0.f; ph[7]=0.f;
    }
    __syncthreads();

    // ---- edge encoder ----
    for (int c0 = 0; c0 < NEDGE; c0 += 36) {
        float4 acc[3]; ZACC4(acc, 3);
        auto fP = [&](int i, int r, int kk) -> float4 {
            return *(const float4*)(s_phys + (c0 + r) * 8 + kk);
        };
        gemm_acc128<8, 36>(s_ew1, fP, acc);
        gemm_fin128<36, true, false>(enc_e_b1, acc, s_t);
        __syncthreads();
        float4 ac2[3]; ZACC4(ac2, 3);
        auto fT = [&](int i, int r, int kk) -> float4 {
            return *(const float4*)(s_t + r * HPAD + kk);
        };
        gemm_acc128<HDIM, 36>(enc_e_w2, fT, ac2);
        gemm_fin128<36, false, false>(enc_e_b2, ac2, s_he + c0 * HPAD);
        __syncthreads();
    }

    // ---- message-passing layers ----
    for (int l = 0; l < NLAYER; ++l) {
        const float* ew1 = edge_w1 + l * 3 * HDIM * HDIM;
        const float* eb1 = edge_b1 + l * HDIM;
        const float* ew2 = edge_w2 + l * HDIM * HDIM;
        const float* eb2 = edge_b2 + l * HDIM;

        for (int c0 = 0; c0 < NEDGE; c0 += 36) {
            Map128 m = map128();
            int baseS[3], baseD[3];
#pragma unroll
            for (int i = 0; i < 3; ++i) {
                const int r = m.rslot + i * 16;
                const int e = c0 + ((r < 36) ? r : 0);
                baseS[i] = s_src[e] * HPAD;
                baseD[i] = s_dst[e] * HPAD;
            }
            float4 acc[3]; ZACC4(acc, 3);
            gemm_acc128<HDIM, 36>(ew1, [&](int i, int r, int kk) -> float4 {
                return *(const float4*)(s_hn + baseS[i] + kk); }, acc);
            gemm_acc128<HDIM, 36>(ew1 + HDIM * HDIM, [&](int i, int r, int kk) -> float4 {
                return *(const float4*)(s_hn + baseD[i] + kk); }, acc);
            gemm_acc128<HDIM, 36>(ew1 + 2 * HDIM * HDIM, [&](int i, int r, int kk) -> float4 {
                return *(const float4*)(s_he + (c0 + r) * HPAD + kk); }, acc);
            gemm_fin128<36, true, false>(eb1, acc, s_t);
            __syncthreads();
            float4 ac2[3]; ZACC4(ac2, 3);
            gemm_acc128<HDIM, 36>(ew2, [&](int i, int r, int kk) -> float4 {
                return *(const float4*)(s_t + r * HPAD + kk); }, ac2);
            gemm_fin128<36, false, true>(eb2, ac2, s_he + c0 * HPAD);   // residual add
            __syncthreads();
        }

        // node update: complete graph -> agg[n] = (sum - h_n[n]) / 8
        if (tid < HDIM) {
            float s = 0.f;
#pragma unroll
            for (int n = 0; n < NSENS; ++n) s += s_hn[n * HPAD + tid];
            s_sum[tid] = s;
        }
        __syncthreads();
        float4 an[1]; ZACC4(an, 1);
        gemm_acc128<HDIM, NSENS>(node_w1 + l * 2 * HDIM * HDIM,
            [&](int i, int r, int kk) -> float4 {
                return *(const float4*)(s_hn + r * HPAD + kk); }, an);
        gemm_acc128<HDIM, NSENS>(node_w1 + l * 2 * HDIM * HDIM + HDIM * HDIM,
            [&](int i, int r, int kk) -> float4 {
                float4 a = *(const float4*)(s_hn + r * HPAD + kk);
                float4 s = *(const float4*)(s_sum + kk);
                return make_float4((s.x-a.x)*0.125f, (s.y-a.y)*0.125f,
                                   (s.z-a.z)*0.125f, (s.w-a.w)*0.125f); }, an);
        gemm_fin128<NSENS, true, false>(node_b1 + l * HDIM, an, s_t);
        __syncthreads();
        float4 an2[1]; ZACC4(an2, 1);
        gemm_acc128<HDIM, NSENS>(node_w2 + l * HDIM * HDIM,
            [&](int i, int r, int kk) -> float4 {
                return *(const float4*)(s_t + r * HPAD + kk); }, an2);
        gemm_fin128<NSENS, false, true>(node_b2 + l * HDIM, an2, s_hn); // residual add
        __syncthreads();
    }

    // ---- decoder ----
    for (int c0 = 0; c0 < NEDGE; c0 += 36) {
        float4 ad[2]; ZACC4(ad, 2);
        gemm_acc64<HDIM, 36>(dec_w1, [&](int i, int r, int kk) -> float4 {
            return *(const float4*)(s_he + (c0 + r) * HPAD + kk); }, ad);
        gemm_fin64<36, true>(dec_b1, ad, s_t, 68);
        __syncthreads();
        if (tid < 36) {
            float a = dec_b2[0];
            const float* tt = s_t + tid * 68;
#pragma unroll
            for (int k = 0; k < 64; ++k) a = fmaf(tt[k], dec_w2[k], a);
            s_val[c0 + tid] = 1.f / (1.f + expf(-a));
        }
        __syncthreads();
    }
    if (tid < NPAIR)
        out[g * NPAIR + tid] = 0.5f * (s_val[2 * tid] + s_val[2 * tid + 1]);
}

extern "C" void kernel_launch(void* const* d_in, const int* in_sizes, int n_in,
                              void* d_out, int out_size, void* d_ws, size_t ws_size,
                              hipStream_t stream) {
    const float* x_nodes     = (const float*)d_in[0];
    const float* damage_locs = (const float*)d_in[1];
    const float* enc_n_w  = (const float*)d_in[2];
    const float* enc_n_b  = (const float*)d_in[3];
    const float* enc_e_w1 = (const float*)d_in[4];
    const float* enc_e_b1 = (const float*)d_in[5];
    const float* enc_e_w2 = (const float*)d_in[6];
    const float* enc_e_b2 = (const float*)d_in[7];
    const float* edge_w1  = (const float*)d_in[8];
    const float* edge_b1  = (const float*)d_in[9];
    const float* edge_w2  = (const float*)d_in[10];
    const float* edge_b2  = (const float*)d_in[11];
    const float* node_w1  = (const float*)d_in[12];
    const float* node_b1  = (const float*)d_in[13];
    const float* node_w2  = (const float*)d_in[14];
    const float* node_b2  = (const float*)d_in[15];
    const float* dec_w1   = (const float*)d_in[16];
    const float* dec_b1   = (const float*)d_in[17];
    const float* dec_w2   = (const float*)d_in[18];
    const float* dec_b2   = (const float*)d_in[19];
    float* out = (float*)d_out;

    const int ngraph = in_sizes[1] / 2;   // damage_locs is [B,2]
    hipLaunchKernelGGL(gnn_fused, dim3(ngraph), dim3(512), 0, stream,
                       x_nodes, damage_locs,
                       enc_n_w, enc_n_b, enc_e_w1, enc_e_b1, enc_e_w2, enc_e_b2,
                       edge_w1, edge_b1, edge_w2, edge_b2,
                       node_w1, node_b1, node_w2, node_b2,
                       dec_w1, dec_b1, dec_w2, dec_b2, out);
}

// Round 4
// 430.721 us; speedup vs baseline: 21.8599x; 12.6571x over previous
//
#include <hip/hip_runtime.h>
#include <math.h>

typedef unsigned short u16;
typedef __attribute__((ext_vector_type(8))) short bf16x8;
typedef __attribute__((ext_vector_type(4))) float f32x4;

#define NSENS 9
#define NEDGE 72
#define NPAIR 36
#define HDIM 128
#define NLAYER 4
#define FEPS 1e-8f

#define ST    136   // bf16 row stride for 128-wide mirrors (272B = 68 dw -> 4-bank skew)
#define STNIN 264   // [h_n | agg] stride (528B)
#define STPH  40    // phys stride (80B), K padded 6->32

__device__ __forceinline__ u16 f2bf(float f) {           // RNE fp32->bf16
    unsigned u = __float_as_uint(f);
    return (u16)((u + 0x7FFFu + ((u >> 16) & 1u)) >> 16);
}
__device__ __forceinline__ float bf2f(u16 h) { return __uint_as_float(((unsigned)h) << 16); }

// ---- packed-weight layout offsets in d_ws (u16 units) ----
// B-fragment order: block(kb,nt) = 512 u16, element ((kb*NT+nt)*64 + lane)*8 + j,
// holding W[kb*32 + (lane>>4)*8 + j][nt*16 + (lane&15)]  (zero-padded past Ksrc).
#define SZ_EE1 (1*8*512)
#define SZ_EE2 (4*8*512)
#define SZ_EW1 (12*8*512)
#define SZ_EW2 (4*8*512)
#define SZ_NW1 (8*8*512)
#define SZ_NW2 (4*8*512)
#define SZ_DW1 (4*4*512)
#define OFF_EE1 0
#define OFF_EE2 (OFF_EE1 + SZ_EE1)
#define OFF_EW1 (OFF_EE2 + SZ_EE2)
#define OFF_EW2 (OFF_EW1 + 4*SZ_EW1)
#define OFF_NW1 (OFF_EW2 + 4*SZ_EW2)
#define OFF_NW2 (OFF_NW1 + 4*SZ_NW1)
#define OFF_DW1 (OFF_NW2 + 4*SZ_NW2)

__global__ void pack_w(const float* __restrict__ src, u16* __restrict__ dst,
                       int Ksrc, int N, int NT, int ls, int ld) {
    const int l  = blockIdx.y;
    const int kb = blockIdx.x / NT, nt = blockIdx.x % NT;
    const int ln = threadIdx.x, q = ln >> 4, c = ln & 15;
    const int n  = nt * 16 + c;
    const float* s = src + l * ls;
    u16* d = dst + l * ld + ((kb * NT + nt) * 64 + ln) * 8;
#pragma unroll
    for (int j = 0; j < 8; ++j) {
        int k = kb * 32 + q * 8 + j;
        d[j] = f2bf((k < Ksrc) ? s[k * N + n] : 0.f);
    }
}

// Wave-level GEMM: acc[mt] += A-frags(fa) @ B-frags(packed global). NT = N/16.
template<int NMT, int NKB, int NT, typename FA>
__device__ __forceinline__ void wave_gemm(const u16* __restrict__ Wp, int nt, int ln,
                                          FA fa, f32x4* acc) {
    const u16* wp = Wp + (nt * 64 + ln) * 8;
#pragma unroll
    for (int kb = 0; kb < NKB; ++kb) {
        bf16x8 b = *(const bf16x8*)(wp + kb * NT * 512);
#pragma unroll
        for (int mt = 0; mt < NMT; ++mt) {
            bf16x8 a = fa(mt, kb);
            acc[mt] = __builtin_amdgcn_mfma_f32_16x16x32_bf16(a, b, acc[mt], 0, 0, 0);
        }
    }
}

#define ZACC(A, N) do { _Pragma("unroll") for (int _i = 0; _i < (N); ++_i) \
                        (A)[_i] = (f32x4){0.f, 0.f, 0.f, 0.f}; } while (0)

// One block (512 thr = 8 waves) per graph. bf16 activation mirrors in LDS;
// fp32 residual masters (h_e, h_n) live in registers with fixed tile ownership
// (wave w always owns n-tile w). MFMA C/D: col=lane&15, row=(lane>>4)*4+reg.
extern "C" __global__ void __launch_bounds__(512, 2)
gnn_mfma(const float* __restrict__ x_nodes, const float* __restrict__ damage_locs,
         const float* __restrict__ enc_n_w, const float* __restrict__ enc_n_b,
         const float* __restrict__ enc_e_b1, const float* __restrict__ enc_e_b2,
         const float* __restrict__ edge_b1, const float* __restrict__ edge_b2,
         const float* __restrict__ node_b1, const float* __restrict__ node_b2,
         const float* __restrict__ dec_b1, const float* __restrict__ dec_w2,
         const float* __restrict__ dec_b2,
         const u16* __restrict__ wpack, float* __restrict__ out)
{
    __shared__ __align__(16) u16 b_he[80 * ST];
    __shared__ __align__(16) u16 b_t [80 * ST];
    __shared__ __align__(16) u16 b_hn[16 * ST];
    __shared__ __align__(16) u16 b_nt[16 * ST];
    __shared__ __align__(16) u16 b_nin[16 * STNIN];
    __shared__ __align__(16) u16 b_ph[80 * STPH];
    __shared__ float s_x[NSENS * 2];
    __shared__ float s_dmg[2];
    __shared__ float s_val[NEDGE];
    __shared__ int s_src[NEDGE], s_dst[NEDGE];

    const int g   = blockIdx.x;
    const int tid = threadIdx.x;
    const int wv  = tid >> 6, ln = tid & 63;
    const int q   = ln >> 4,  cl = ln & 15;
    const int col = wv * 16 + cl;          // this wave's output column (128-wide GEMMs)

    // ---- zero mirrors (pads must be 0), stage inputs, static tables ----
    for (int i = tid; i < 80 * ST; i += 512) { b_he[i] = 0; b_t[i] = 0; }
    for (int i = tid; i < 16 * ST; i += 512) { b_hn[i] = 0; b_nt[i] = 0; }
    for (int i = tid; i < 16 * STNIN; i += 512) b_nin[i] = 0;
    for (int i = tid; i < 80 * STPH;  i += 512) b_ph[i] = 0;
    if (tid < NSENS * 2) s_x[tid] = x_nodes[g * NSENS * 2 + tid];
    if (tid < 2)         s_dmg[tid] = damage_locs[g * 2 + tid];
    if (tid < NEDGE) {
        int p = tid >> 1;
        int i = 0, rem = p, cnt = 8;
        while (rem >= cnt) { rem -= cnt; --cnt; ++i; }
        int j = i + 1 + rem;
        s_src[tid] = (tid & 1) ? j : i;
        s_dst[tid] = (tid & 1) ? i : j;
    }
    __syncthreads();

    // ---- phys features -> b_ph (bf16, rows<72, cols 0..5 of 32) ----
    if (tid < NEDGE) {
        const int si = s_src[tid], di = s_dst[tid];
        const float sx = s_x[2*si], sy = s_x[2*si+1];
        const float dx = s_x[2*di], dy = s_x[2*di+1];
        const float gx = s_dmg[0],  gy = s_dmg[1];
        const float vx = sx - dx, vy = sy - dy;
        const float vv = vx*vx + vy*vy;
        const float elen = sqrtf(vv + FEPS);
        const float l2 = fmaxf(vv, FEPS);
        float t = ((gx - sx) * (dx - sx) + (gy - sy) * (dy - sy)) / l2;
        t = fminf(fmaxf(t, 0.f), 1.f);
        const float px = sx + t * (dx - sx), py = sy + t * (dy - sy);
        u16* ph = b_ph + tid * STPH;
        ph[0] = f2bf(vx); ph[1] = f2bf(vy); ph[2] = f2bf(elen);
        ph[3] = f2bf(sqrtf((gx-px)*(gx-px) + (gy-py)*(gy-py) + FEPS));
        ph[4] = f2bf(sqrtf((sx-gx)*(sx-gx) + (sy-gy)*(sy-gy) + FEPS));
        ph[5] = f2bf(sqrtf((dx-gx)*(dx-gx) + (dy-gy)*(dy-gy) + FEPS));
    }

    // ---- node encoder (K=2) -> fp32 master m_hn + bf16 mirror ----
    f32x4 m_hn;
    {
        const float w0 = enc_n_w[col], w1 = enc_n_w[HDIM + col], bb = enc_n_b[col];
#pragma unroll
        for (int r = 0; r < 4; ++r) {
            const int R = q * 4 + r;
            float v = (R < NSENS) ? fmaf(s_x[2*R], w0, fmaf(s_x[2*R+1], w1, bb)) : 0.f;
            m_hn[r] = v;
            b_hn[R * ST + col] = f2bf(v);   // R<16 always; pad rows get 0
        }
    }
    __syncthreads();

    // per-lane edge-row indirection offsets (constant across layers)
    int rowS[5], rowD[5], rowE[5];
#pragma unroll
    for (int mt = 0; mt < 5; ++mt) {
        int e = mt * 16 + cl; if (e >= NEDGE) e = NEDGE - 1;
        rowS[mt] = s_src[e] * ST; rowD[mt] = s_dst[e] * ST; rowE[mt] = e * ST;
    }

    auto fa_t   = [&](int mt, int kb) -> bf16x8 {
        return *(const bf16x8*)(b_t + (mt * 16 + cl) * ST + kb * 32 + q * 8); };
    auto fa_he  = [&](int mt, int kb) -> bf16x8 {
        return *(const bf16x8*)(b_he + (mt * 16 + cl) * ST + kb * 32 + q * 8); };
    auto fa_ph  = [&](int mt, int kb) -> bf16x8 {
        return *(const bf16x8*)(b_ph + (mt * 16 + cl) * STPH + q * 8); };
    auto fa_nin = [&](int mt, int kb) -> bf16x8 {
        return *(const bf16x8*)(b_nin + cl * STNIN + kb * 32 + q * 8); };
    auto fa_nt  = [&](int mt, int kb) -> bf16x8 {
        return *(const bf16x8*)(b_nt + cl * ST + kb * 32 + q * 8); };
    auto fa_ein = [&](int mt, int kb) -> bf16x8 {
        const u16* p;
        if (kb < 4)      p = b_hn + rowS[mt] + kb * 32;
        else if (kb < 8) p = b_hn + rowD[mt] + (kb - 4) * 32;
        else             p = b_he + rowE[mt] + (kb - 8) * 32;
        return *(const bf16x8*)(p + q * 8); };

    f32x4 m_he[5];

    // ---- edge encoder GEMM1: relu(phys @ W1 + b1) -> b_t ----
    {
        f32x4 acc[5]; ZACC(acc, 5);
        wave_gemm<5, 1, 8>(wpack + OFF_EE1, wv, ln, fa_ph, acc);
        const float bb = enc_e_b1[col];
#pragma unroll
        for (int mt = 0; mt < 5; ++mt)
#pragma unroll
            for (int r = 0; r < 4; ++r) {
                const int R = mt * 16 + q * 4 + r;
                if (R < NEDGE) b_t[R * ST + col] = f2bf(fmaxf(acc[mt][r] + bb, 0.f));
            }
    }
    __syncthreads();
    // ---- edge encoder GEMM2 -> m_he (init), b_he ----
    {
        f32x4 acc[5]; ZACC(acc, 5);
        wave_gemm<5, 4, 8>(wpack + OFF_EE2, wv, ln, fa_t, acc);
        const float bb = enc_e_b2[col];
#pragma unroll
        for (int mt = 0; mt < 5; ++mt)
#pragma unroll
            for (int r = 0; r < 4; ++r) {
                const int R = mt * 16 + q * 4 + r;
                m_he[mt][r] = acc[mt][r] + bb;
                if (R < NEDGE) b_he[R * ST + col] = f2bf(m_he[mt][r]);
            }
    }
    __syncthreads();

    // ---- message-passing layers ----
    for (int l = 0; l < NLAYER; ++l) {
        // edge MLP1: relu([h_src|h_dst|h_e] @ W1 + b1) -> b_t
        {
            f32x4 acc[5]; ZACC(acc, 5);
            wave_gemm<5, 12, 8>(wpack + OFF_EW1 + l * SZ_EW1, wv, ln, fa_ein, acc);
            const float bb = edge_b1[l * HDIM + col];
#pragma unroll
            for (int mt = 0; mt < 5; ++mt)
#pragma unroll
                for (int r = 0; r < 4; ++r) {
                    const int R = mt * 16 + q * 4 + r;
                    if (R < NEDGE) b_t[R * ST + col] = f2bf(fmaxf(acc[mt][r] + bb, 0.f));
                }
        }
        __syncthreads();
        // edge MLP2: h_e += hidden @ W2 + b2 (fp32 master), write bf16 mirror
        {
            f32x4 acc[5]; ZACC(acc, 5);
            wave_gemm<5, 4, 8>(wpack + OFF_EW2 + l * SZ_EW2, wv, ln, fa_t, acc);
            const float bb = edge_b2[l * HDIM + col];
#pragma unroll
            for (int mt = 0; mt < 5; ++mt)
#pragma unroll
                for (int r = 0; r < 4; ++r) {
                    const int R = mt * 16 + q * 4 + r;
                    m_he[mt][r] += acc[mt][r] + bb;
                    if (R < NEDGE) b_he[R * ST + col] = f2bf(m_he[mt][r]);
                }
        }
        __syncthreads();
        // node agg: colsum of h_n via cross-lane, write b_nin = [h_n | (sum-h)/8]
        {
            float p4 = m_hn[0] + m_hn[1] + m_hn[2] + m_hn[3]; // pad rows are 0
            p4 += __shfl_xor(p4, 16);
            p4 += __shfl_xor(p4, 32);
#pragma unroll
            for (int r = 0; r < 4; ++r) {
                const int R = q * 4 + r;
                if (R < NSENS) {
                    b_nin[R * STNIN + col]        = f2bf(m_hn[r]);
                    b_nin[R * STNIN + HDIM + col] = f2bf((p4 - m_hn[r]) * 0.125f);
                }
            }
        }
        __syncthreads();
        // node MLP1 -> b_nt
        {
            f32x4 acc[1]; ZACC(acc, 1);
            wave_gemm<1, 8, 8>(wpack + OFF_NW1 + l * SZ_NW1, wv, ln, fa_nin, acc);
            const float bb = node_b1[l * HDIM + col];
#pragma unroll
            for (int r = 0; r < 4; ++r) {
                const int R = q * 4 + r;
                b_nt[R * ST + col] = f2bf(fmaxf(acc[0][r] + bb, 0.f));
            }
        }
        __syncthreads();
        // node MLP2: h_n += hidden @ W2 + b2, write bf16 mirror
        {
            f32x4 acc[1]; ZACC(acc, 1);
            wave_gemm<1, 4, 8>(wpack + OFF_NW2 + l * SZ_NW2, wv, ln, fa_nt, acc);
            const float bb = node_b2[l * HDIM + col];
#pragma unroll
            for (int r = 0; r < 4; ++r) {
                const int R = q * 4 + r;
                if (R < NSENS) {
                    m_hn[r] += acc[0][r] + bb;
                    b_hn[R * ST + col] = f2bf(m_hn[r]);
                }
            }
        }
        __syncthreads();
    }

    // ---- decoder GEMM1 (N=64): relu(h_e @ dec_w1 + b1) -> b_t cols 0..63 ----
    {
        const int ntd = wv & 3;
        const int mt0 = (wv < 4) ? 0 : 2;     // waves 0-3: mt 0-2; waves 4-7: mt 2-4
        f32x4 acc[3]; ZACC(acc, 3);           // (mt=2 computed twice -> benign same-value)
        auto fa_d = [&](int mt, int kb) -> bf16x8 {
            return *(const bf16x8*)(b_he + ((mt0 + mt) * 16 + cl) * ST + kb * 32 + q * 8); };
        wave_gemm<3, 4, 4>(wpack + OFF_DW1, ntd, ln, fa_d, acc);
        const int c64 = ntd * 16 + cl;
        const float bb = dec_b1[c64];
#pragma unroll
        for (int mt = 0; mt < 3; ++mt)
#pragma unroll
            for (int r = 0; r < 4; ++r) {
                const int R = (mt0 + mt) * 16 + q * 4 + r;
                if (R < NEDGE) b_t[R * ST + c64] = f2bf(fmaxf(acc[mt][r] + bb, 0.f));
            }
    }
    __syncthreads();
    // ---- decoder GEMM2 (N=1) + sigmoid ----
    if (tid < NEDGE) {
        float a = dec_b2[0];
        const u16* tt = b_t + tid * ST;
#pragma unroll
        for (int k = 0; k < 64; ++k) a = fmaf(bf2f(tt[k]), dec_w2[k], a);
        s_val[tid] = 1.f / (1.f + expf(-a));
    }
    __syncthreads();
    if (tid < NPAIR)
        out[g * NPAIR + tid] = 0.5f * (s_val[2 * tid] + s_val[2 * tid + 1]);
}

extern "C" void kernel_launch(void* const* d_in, const int* in_sizes, int n_in,
                              void* d_out, int out_size, void* d_ws, size_t ws_size,
                              hipStream_t stream) {
    const float* x_nodes     = (const float*)d_in[0];
    const float* damage_locs = (const float*)d_in[1];
    const float* enc_n_w  = (const float*)d_in[2];
    const float* enc_n_b  = (const float*)d_in[3];
    const float* enc_e_w1 = (const float*)d_in[4];
    const float* enc_e_b1 = (const float*)d_in[5];
    const float* enc_e_w2 = (const float*)d_in[6];
    const float* enc_e_b2 = (const float*)d_in[7];
    const float* edge_w1  = (const float*)d_in[8];
    const float* edge_b1  = (const float*)d_in[9];
    const float* edge_w2  = (const float*)d_in[10];
    const float* edge_b2  = (const float*)d_in[11];
    const float* node_w1  = (const float*)d_in[12];
    const float* node_b1  = (const float*)d_in[13];
    const float* node_w2  = (const float*)d_in[14];
    const float* node_b2  = (const float*)d_in[15];
    const float* dec_w1   = (const float*)d_in[16];
    const float* dec_b1   = (const float*)d_in[17];
    const float* dec_w2   = (const float*)d_in[18];
    const float* dec_b2   = (const float*)d_in[19];
    float* out = (float*)d_out;
    u16* ws = (u16*)d_ws;

    // pack weights (bf16, B-fragment order) into workspace
    hipLaunchKernelGGL(pack_w, dim3(1*8, 1),  dim3(64), 0, stream, enc_e_w1, ws + OFF_EE1, 6,   128, 8, 0, 0);
    hipLaunchKernelGGL(pack_w, dim3(4*8, 1),  dim3(64), 0, stream, enc_e_w2, ws + OFF_EE2, 128, 128, 8, 0, 0);
    hipLaunchKernelGGL(pack_w, dim3(12*8, 4), dim3(64), 0, stream, edge_w1,  ws + OFF_EW1, 384, 128, 8, 384*128, SZ_EW1);
    hipLaunchKernelGGL(pack_w, dim3(4*8, 4),  dim3(64), 0, stream, edge_w2,  ws + OFF_EW2, 128, 128, 8, 128*128, SZ_EW2);
    hipLaunchKernelGGL(pack_w, dim3(8*8, 4),  dim3(64), 0, stream, node_w1,  ws + OFF_NW1, 256, 128, 8, 256*128, SZ_NW1);
    hipLaunchKernelGGL(pack_w, dim3(4*8, 4),  dim3(64), 0, stream, node_w2,  ws + OFF_NW2, 128, 128, 8, 128*128, SZ_NW2);
    hipLaunchKernelGGL(pack_w, dim3(4*4, 1),  dim3(64), 0, stream, dec_w1,   ws + OFF_DW1, 128, 64,  4, 0, 0);

    const int ngraph = in_sizes[1] / 2;   // damage_locs is [B,2]
    hipLaunchKernelGGL(gnn_mfma, dim3(ngraph), dim3(512), 0, stream,
                       x_nodes, damage_locs, enc_n_w, enc_n_b,
                       enc_e_b1, enc_e_b2, edge_b1, edge_b2,
                       node_b1, node_b2, dec_b1, dec_w2, dec_b2,
                       ws, out);
}

// Round 5
// 402.163 us; speedup vs baseline: 23.4122x; 1.0710x over previous
//
#include <hip/hip_runtime.h>
#include <math.h>

typedef unsigned short u16;
typedef __attribute__((ext_vector_type(8))) short bf16x8;
typedef __attribute__((ext_vector_type(4))) float f32x4;

#define NSENS 9
#define NEDGE 72
#define NPAIR 36
#define HDIM 128
#define NLAYER 4
#define FEPS 1e-8f

#define ST    136   // bf16 row stride (272B = 17 quads, odd -> conflict-free b128 reads)
#define STNIN 264   // [h_n | agg] row stride
#define STPH  40    // phys row stride, K padded 6->32

__device__ __forceinline__ u16 f2bf(float f) {           // RNE fp32->bf16
    unsigned u = __float_as_uint(f);
    return (u16)((u + 0x7FFFu + ((u >> 16) & 1u)) >> 16);
}
__device__ __forceinline__ float bf2f(u16 h) { return __uint_as_float(((unsigned)h) << 16); }
__device__ __forceinline__ unsigned pkbf(float lo, float hi) {
    return ((unsigned)f2bf(hi) << 16) | (unsigned)f2bf(lo);
}

// ---- packed-weight layout offsets in d_ws (u16 units) ----
// B-fragment order: block(kb,nt) = 512 u16, element ((kb*NT+nt)*64 + lane)*8 + j,
// holding W[kb*32 + (lane>>4)*8 + j][nt*16 + (lane&15)]  (zero-padded past Ksrc).
#define SZ_EE1 (1*8*512)
#define SZ_EE2 (4*8*512)
#define SZ_EW1 (12*8*512)
#define SZ_EW2 (4*8*512)
#define SZ_NW1 (8*8*512)
#define SZ_NW2 (4*8*512)
#define SZ_DW1 (4*4*512)
#define OFF_EE1 0
#define OFF_EE2 (OFF_EE1 + SZ_EE1)
#define OFF_EW1 (OFF_EE2 + SZ_EE2)
#define OFF_EW2 (OFF_EW1 + 4*SZ_EW1)
#define OFF_NW1 (OFF_EW2 + 4*SZ_EW2)
#define OFF_NW2 (OFF_NW1 + 4*SZ_NW1)
#define OFF_DW1 (OFF_NW2 + 4*SZ_NW2)

__device__ __forceinline__ void pack_one(const float* __restrict__ s, u16* __restrict__ d,
                                         int Ksrc, int N, int NT, int kbnt) {
    const int kb = kbnt / NT, nt = kbnt % NT;
    const int ln = threadIdx.x, q = ln >> 4, c = ln & 15;
    const int n  = nt * 16 + c;
    u16* dp = d + ((kb * NT + nt) * 64 + ln) * 8;
#pragma unroll
    for (int j = 0; j < 8; ++j) {
        int k = kb * 32 + q * 8 + j;
        dp[j] = f2bf((k < Ksrc) ? s[k * N + n] : 0.f);
    }
}

// Single merged pack kernel: grid.x = 952 blocks x 64 threads.
__global__ void pack_all(const float* __restrict__ ee1, const float* __restrict__ ee2,
                         const float* __restrict__ ew1, const float* __restrict__ ew2,
                         const float* __restrict__ nw1, const float* __restrict__ nw2,
                         const float* __restrict__ dw1, u16* __restrict__ ws) {
    int b = blockIdx.x;
    if (b < 8)        { pack_one(ee1, ws + OFF_EE1, 6, 128, 8, b); return; }
    b -= 8;
    if (b < 32)       { pack_one(ee2, ws + OFF_EE2, 128, 128, 8, b); return; }
    b -= 32;
    if (b < 384)      { int l = b / 96;
                        pack_one(ew1 + l*384*128, ws + OFF_EW1 + l*SZ_EW1, 384, 128, 8, b % 96); return; }
    b -= 384;
    if (b < 128)      { int l = b / 32;
                        pack_one(ew2 + l*128*128, ws + OFF_EW2 + l*SZ_EW2, 128, 128, 8, b % 32); return; }
    b -= 128;
    if (b < 256)      { int l = b / 64;
                        pack_one(nw1 + l*256*128, ws + OFF_NW1 + l*SZ_NW1, 256, 128, 8, b % 64); return; }
    b -= 256;
    if (b < 128)      { int l = b / 32;
                        pack_one(nw2 + l*128*128, ws + OFF_NW2 + l*SZ_NW2, 128, 128, 8, b % 32); return; }
    b -= 128;
    pack_one(dw1, ws + OFF_DW1, 128, 64, 4, b);
}

// Wave-level GEMM: acc[mt] += A-frags(fa) @ B-frags(packed global). NT = N/16.
template<int NMT, int NKB, int NT, typename FA>
__device__ __forceinline__ void wave_gemm(const u16* __restrict__ Wp, int nt, int ln,
                                          FA fa, f32x4* acc) {
    const u16* wp = Wp + (nt * 64 + ln) * 8;
#pragma unroll
    for (int kb = 0; kb < NKB; ++kb) {
        bf16x8 b = *(const bf16x8*)(wp + kb * NT * 512);
#pragma unroll
        for (int mt = 0; mt < NMT; ++mt) {
            bf16x8 a = fa(mt, kb);
            acc[mt] = __builtin_amdgcn_mfma_f32_16x16x32_bf16(a, b, acc[mt], 0, 0, 0);
        }
    }
}

#define ZACC(A, N) do { _Pragma("unroll") for (int _i = 0; _i < (N); ++_i) \
                        (A)[_i] = (f32x4){0.f, 0.f, 0.f, 0.f}; } while (0)

// One block (512 thr = 8 waves) per graph. bf16 activation mirrors in LDS (~53 KB
// with aliasing -> 3 blocks/CU); fp32 residual masters (h_e, h_n) in registers with
// fixed tile ownership. MFMA C/D: col=lane&15, row=(lane>>4)*4+reg.
extern "C" __global__ void __launch_bounds__(512, 2)
gnn_mfma(const float* __restrict__ x_nodes, const float* __restrict__ damage_locs,
         const float* __restrict__ enc_n_w, const float* __restrict__ enc_n_b,
         const float* __restrict__ enc_e_b1, const float* __restrict__ enc_e_b2,
         const float* __restrict__ edge_b1, const float* __restrict__ edge_b2,
         const float* __restrict__ node_b1, const float* __restrict__ node_b2,
         const float* __restrict__ dec_b1, const float* __restrict__ dec_w2,
         const float* __restrict__ dec_b2,
         const u16* __restrict__ wpack, float* __restrict__ out)
{
    __shared__ __align__(16) u16 smem[192 * ST];
    __shared__ float s_x[NSENS * 2];
    __shared__ float s_dmg[2];
    __shared__ float s_val[NEDGE];
    __shared__ int s_src[NEDGE], s_dst[NEDGE];

    u16* b_he  = smem;               // 80*ST  edge features (bf16 mirror)
    u16* b_t   = smem + 80 * ST;     // 80*ST  MLP hidden
    u16* b_hn  = smem + 160 * ST;    // 16*ST  node features
    u16* b_nt  = smem + 176 * ST;    // 16*ST  node hidden
    u16* b_ph  = b_he;               // alias: phys dead once EE1 consumed it
    u16* b_nin = b_t;                // alias: [h_n|agg], live only agg -> node MLP1

    const int g   = blockIdx.x;
    const int tid = threadIdx.x;
    const int wv  = tid >> 6, ln = tid & 63;
    const int q   = ln >> 4,  cl = ln & 15;
    const int col = wv * 16 + cl;          // this wave's output column (128-wide GEMMs)

    // paired bf16x2 store: lane pairs (cl, cl^1) swap halves so each lane writes
    // full dwords (2 cols x 1 row) -> half the stores, no subword-merge conflicts.
    auto stp = [&](u16* buf, int stride, int c, int Rb, int Rlim,
                   float v0, float v1, float v2, float v3) {
        const bool od = cl & 1;
        float x = od ? v0 : v2, y = od ? v1 : v3;
        float px = __shfl_xor(x, 1), py = __shfl_xor(y, 1);
        float lo0 = od ? px : v0, hi0 = od ? v2 : px;
        float lo1 = od ? py : v1, hi1 = od ? v3 : py;
        const int r0 = Rb + (od ? 2 : 0);
        const int cc = c & ~1;
        if (r0 < Rlim)     *(unsigned*)(buf + r0 * stride + cc)       = pkbf(lo0, hi0);
        if (r0 + 1 < Rlim) *(unsigned*)(buf + (r0 + 1) * stride + cc) = pkbf(lo1, hi1);
    };

    // ---- vectorized zero of all mirrors (pads must be 0), stage inputs ----
    {
        uint4 z = {0, 0, 0, 0};
        uint4* zp = (uint4*)smem;
        for (int i = tid; i < (192 * ST * 2) / 16; i += 512) zp[i] = z;
    }
    if (tid < NSENS * 2) s_x[tid] = x_nodes[g * NSENS * 2 + tid];
    if (tid < 2)         s_dmg[tid] = damage_locs[g * 2 + tid];
    if (tid < NEDGE) {
        int p = tid >> 1;
        int i = 0, rem = p, cnt = 8;
        while (rem >= cnt) { rem -= cnt; --cnt; ++i; }
        int j = i + 1 + rem;
        s_src[tid] = (tid & 1) ? j : i;
        s_dst[tid] = (tid & 1) ? i : j;
    }
    __syncthreads();

    // ---- phys features -> b_ph (rows<72, cols 0..5 of 32) ----
    if (tid < NEDGE) {
        const int si = s_src[tid], di = s_dst[tid];
        const float sx = s_x[2*si], sy = s_x[2*si+1];
        const float dx = s_x[2*di], dy = s_x[2*di+1];
        const float gx = s_dmg[0],  gy = s_dmg[1];
        const float vx = sx - dx, vy = sy - dy;
        const float vv = vx*vx + vy*vy;
        const float elen = sqrtf(vv + FEPS);
        const float l2 = fmaxf(vv, FEPS);
        float t = ((gx - sx) * (dx - sx) + (gy - sy) * (dy - sy)) / l2;
        t = fminf(fmaxf(t, 0.f), 1.f);
        const float px = sx + t * (dx - sx), py = sy + t * (dy - sy);
        u16* ph = b_ph + tid * STPH;
        ph[0] = f2bf(vx); ph[1] = f2bf(vy); ph[2] = f2bf(elen);
        ph[3] = f2bf(sqrtf((gx-px)*(gx-px) + (gy-py)*(gy-py) + FEPS));
        ph[4] = f2bf(sqrtf((sx-gx)*(sx-gx) + (sy-gy)*(sy-gy) + FEPS));
        ph[5] = f2bf(sqrtf((dx-gx)*(dx-gx) + (dy-gy)*(dy-gy) + FEPS));
    }

    // ---- node encoder (K=2) -> fp32 master m_hn + bf16 mirror ----
    f32x4 m_hn;
    {
        const float w0 = enc_n_w[col], w1 = enc_n_w[HDIM + col], bb = enc_n_b[col];
#pragma unroll
        for (int r = 0; r < 4; ++r) {
            const int R = q * 4 + r;
            m_hn[r] = (R < NSENS) ? fmaf(s_x[2*R], w0, fmaf(s_x[2*R+1], w1, bb)) : 0.f;
        }
        stp(b_hn, ST, col, q * 4, NSENS, m_hn[0], m_hn[1], m_hn[2], m_hn[3]);
    }

    // per-lane edge-row indirection offsets (constant across layers)
    int rowS[5], rowD[5], rowE[5];
#pragma unroll
    for (int mt = 0; mt < 5; ++mt) {
        int e = mt * 16 + cl; if (e >= NEDGE) e = NEDGE - 1;
        rowS[mt] = s_src[e] * ST; rowD[mt] = s_dst[e] * ST; rowE[mt] = e * ST;
    }
    __syncthreads();

    auto fa_t   = [&](int mt, int kb) -> bf16x8 {
        return *(const bf16x8*)(b_t + (mt * 16 + cl) * ST + kb * 32 + q * 8); };
    auto fa_ph  = [&](int mt, int kb) -> bf16x8 {
        return *(const bf16x8*)(b_ph + (mt * 16 + cl) * STPH + q * 8); };
    auto fa_nin = [&](int mt, int kb) -> bf16x8 {
        return *(const bf16x8*)(b_nin + cl * STNIN + kb * 32 + q * 8); };
    auto fa_nt  = [&](int mt, int kb) -> bf16x8 {
        return *(const bf16x8*)(b_nt + cl * ST + kb * 32 + q * 8); };
    auto fa_ein = [&](int mt, int kb) -> bf16x8 {
        const u16* p;
        if (kb < 4)      p = b_hn + rowS[mt] + kb * 32;
        else if (kb < 8) p = b_hn + rowD[mt] + (kb - 4) * 32;
        else             p = b_he + rowE[mt] + (kb - 8) * 32;
        return *(const bf16x8*)(p + q * 8); };

    f32x4 m_he[5];

    // ---- edge encoder GEMM1: relu(phys @ W1 + b1) -> b_t ----
    {
        f32x4 acc[5]; ZACC(acc, 5);
        wave_gemm<5, 1, 8>(wpack + OFF_EE1, wv, ln, fa_ph, acc);
        const float bb = enc_e_b1[col];
#pragma unroll
        for (int mt = 0; mt < 5; ++mt)
            stp(b_t, ST, col, mt * 16 + q * 4, NEDGE,
                fmaxf(acc[mt][0] + bb, 0.f), fmaxf(acc[mt][1] + bb, 0.f),
                fmaxf(acc[mt][2] + bb, 0.f), fmaxf(acc[mt][3] + bb, 0.f));
    }
    __syncthreads();
    // ---- edge encoder GEMM2 -> m_he (init), b_he (overwrites phys region) ----
    {
        f32x4 acc[5]; ZACC(acc, 5);
        wave_gemm<5, 4, 8>(wpack + OFF_EE2, wv, ln, fa_t, acc);
        const float bb = enc_e_b2[col];
#pragma unroll
        for (int mt = 0; mt < 5; ++mt) {
#pragma unroll
            for (int r = 0; r < 4; ++r) m_he[mt][r] = acc[mt][r] + bb;
            stp(b_he, ST, col, mt * 16 + q * 4, NEDGE,
                m_he[mt][0], m_he[mt][1], m_he[mt][2], m_he[mt][3]);
        }
    }
    __syncthreads();

    // ---- message-passing layers ----
    for (int l = 0; l < NLAYER; ++l) {
        // edge MLP1: relu([h_src|h_dst|h_e] @ W1 + b1) -> b_t
        {
            f32x4 acc[5]; ZACC(acc, 5);
            wave_gemm<5, 12, 8>(wpack + OFF_EW1 + l * SZ_EW1, wv, ln, fa_ein, acc);
            const float bb = edge_b1[l * HDIM + col];
#pragma unroll
            for (int mt = 0; mt < 5; ++mt)
                stp(b_t, ST, col, mt * 16 + q * 4, NEDGE,
                    fmaxf(acc[mt][0] + bb, 0.f), fmaxf(acc[mt][1] + bb, 0.f),
                    fmaxf(acc[mt][2] + bb, 0.f), fmaxf(acc[mt][3] + bb, 0.f));
        }
        __syncthreads();
        // edge MLP2: h_e += hidden @ W2 + b2 (fp32 master), refresh bf16 mirror
        {
            f32x4 acc[5]; ZACC(acc, 5);
            wave_gemm<5, 4, 8>(wpack + OFF_EW2 + l * SZ_EW2, wv, ln, fa_t, acc);
            const float bb = edge_b2[l * HDIM + col];
#pragma unroll
            for (int mt = 0; mt < 5; ++mt) {
#pragma unroll
                for (int r = 0; r < 4; ++r) m_he[mt][r] += acc[mt][r] + bb;
                stp(b_he, ST, col, mt * 16 + q * 4, NEDGE,
                    m_he[mt][0], m_he[mt][1], m_he[mt][2], m_he[mt][3]);
            }
        }
        __syncthreads();
        // node agg: colsum via cross-lane; b_nin = [h_n | (sum-h)/8] (aliases b_t;
        // stale rows 9..15 only pollute discarded C rows)
        {
            float p4 = m_hn[0] + m_hn[1] + m_hn[2] + m_hn[3]; // pad rows are 0
            p4 += __shfl_xor(p4, 16);
            p4 += __shfl_xor(p4, 32);
            stp(b_nin, STNIN, col, q * 4, NSENS, m_hn[0], m_hn[1], m_hn[2], m_hn[3]);
            stp(b_nin, STNIN, HDIM + col, q * 4, NSENS,
                (p4 - m_hn[0]) * 0.125f, (p4 - m_hn[1]) * 0.125f,
                (p4 - m_hn[2]) * 0.125f, (p4 - m_hn[3]) * 0.125f);
        }
        __syncthreads();
        // node MLP1 -> b_nt
        {
            f32x4 acc[1]; ZACC(acc, 1);
            wave_gemm<1, 8, 8>(wpack + OFF_NW1 + l * SZ_NW1, wv, ln, fa_nin, acc);
            const float bb = node_b1[l * HDIM + col];
            stp(b_nt, ST, col, q * 4, 16,
                fmaxf(acc[0][0] + bb, 0.f), fmaxf(acc[0][1] + bb, 0.f),
                fmaxf(acc[0][2] + bb, 0.f), fmaxf(acc[0][3] + bb, 0.f));
        }
        __syncthreads();
        // node MLP2: h_n += hidden @ W2 + b2, refresh bf16 mirror (rows<9 only)
        {
            f32x4 acc[1]; ZACC(acc, 1);
            wave_gemm<1, 4, 8>(wpack + OFF_NW2 + l * SZ_NW2, wv, ln, fa_nt, acc);
            const float bb = node_b2[l * HDIM + col];
#pragma unroll
            for (int r = 0; r < 4; ++r)
                if (q * 4 + r < NSENS) m_hn[r] += acc[0][r] + bb;
            stp(b_hn, ST, col, q * 4, NSENS, m_hn[0], m_hn[1], m_hn[2], m_hn[3]);
        }
        __syncthreads();
    }

    // ---- decoder GEMM1 (N=64): relu(h_e @ dec_w1 + b1) -> b_t cols 0..63 ----
    {
        const int ntd = wv & 3;
        const int mt0 = (wv < 4) ? 0 : 2;     // waves 0-3: mt 0-2; waves 4-7: mt 2-4
        f32x4 acc[3]; ZACC(acc, 3);           // (mt=2 computed twice -> same-value race, benign)
        auto fa_d = [&](int mt, int kb) -> bf16x8 {
            return *(const bf16x8*)(b_he + ((mt0 + mt) * 16 + cl) * ST + kb * 32 + q * 8); };
        wave_gemm<3, 4, 4>(wpack + OFF_DW1, ntd, ln, fa_d, acc);
        const int c64 = ntd * 16 + cl;
        const float bb = dec_b1[c64];
#pragma unroll
        for (int mt = 0; mt < 3; ++mt)
            stp(b_t, ST, c64, (mt0 + mt) * 16 + q * 4, NEDGE,
                fmaxf(acc[mt][0] + bb, 0.f), fmaxf(acc[mt][1] + bb, 0.f),
                fmaxf(acc[mt][2] + bb, 0.f), fmaxf(acc[mt][3] + bb, 0.f));
    }
    __syncthreads();
    // ---- decoder GEMM2 (N=1) + sigmoid ----
    if (tid < NEDGE) {
        float a = dec_b2[0];
        const u16* tt = b_t + tid * ST;
#pragma unroll
        for (int k = 0; k < 64; ++k) a = fmaf(bf2f(tt[k]), dec_w2[k], a);
        s_val[tid] = 1.f / (1.f + expf(-a));
    }
    __syncthreads();
    if (tid < NPAIR)
        out[g * NPAIR + tid] = 0.5f * (s_val[2 * tid] + s_val[2 * tid + 1]);
}

extern "C" void kernel_launch(void* const* d_in, const int* in_sizes, int n_in,
                              void* d_out, int out_size, void* d_ws, size_t ws_size,
                              hipStream_t stream) {
    const float* x_nodes     = (const float*)d_in[0];
    const float* damage_locs = (const float*)d_in[1];
    const float* enc_n_w  = (const float*)d_in[2];
    const float* enc_n_b  = (const float*)d_in[3];
    const float* enc_e_w1 = (const float*)d_in[4];
    const float* enc_e_b1 = (const float*)d_in[5];
    const float* enc_e_w2 = (const float*)d_in[6];
    const float* enc_e_b2 = (const float*)d_in[7];
    const float* edge_w1  = (const float*)d_in[8];
    const float* edge_b1  = (const float*)d_in[9];
    const float* edge_w2  = (const float*)d_in[10];
    const float* edge_b2  = (const float*)d_in[11];
    const float* node_w1  = (const float*)d_in[12];
    const float* node_b1  = (const float*)d_in[13];
    const float* node_w2  = (const float*)d_in[14];
    const float* node_b2  = (const float*)d_in[15];
    const float* dec_w1   = (const float*)d_in[16];
    const float* dec_b1   = (const float*)d_in[17];
    const float* dec_w2   = (const float*)d_in[18];
    const float* dec_b2   = (const float*)d_in[19];
    float* out = (float*)d_out;
    u16* ws = (u16*)d_ws;

    // single merged pack launch (bf16, B-fragment order)
    hipLaunchKernelGGL(pack_all, dim3(952), dim3(64), 0, stream,
                       enc_e_w1, enc_e_w2, edge_w1, edge_w2, node_w1, node_w2, dec_w1, ws);

    const int ngraph = in_sizes[1] / 2;   // damage_locs is [B,2]
    hipLaunchKernelGGL(gnn_mfma, dim3(ngraph), dim3(512), 0, stream,
                       x_nodes, damage_locs, enc_n_w, enc_n_b,
                       enc_e_b1, enc_e_b2, edge_b1, edge_b2,
                       node_b1, node_b2, dec_b1, dec_w2, dec_b2,
                       ws, out);
}

// Round 6
// 373.558 us; speedup vs baseline: 25.2050x; 1.0766x over previous
//
#include <hip/hip_runtime.h>
#include <math.h>

typedef unsigned short u16;
typedef __attribute__((ext_vector_type(8))) short bf16x8;
typedef __attribute__((ext_vector_type(4))) float f32x4;

#define NSENS 9
#define NEDGE 72
#define NPAIR 36
#define HDIM 128
#define NLAYER 4
#define FEPS 1e-8f

#define ST    136   // bf16 row stride (272B = 17 quads, odd -> minimal-phase b128 reads)
#define STNIN 264   // [h_n | agg] row stride
#define STPH  40    // phys row stride, K padded 6->32

__device__ __forceinline__ u16 f2bf(float f) {           // RNE fp32->bf16
    unsigned u = __float_as_uint(f);
    return (u16)((u + 0x7FFFu + ((u >> 16) & 1u)) >> 16);
}
__device__ __forceinline__ float bf2f(u16 h) { return __uint_as_float(((unsigned)h) << 16); }

// packed pair cvt: rows (lo,hi) -> one dword, HW v_cvt_pk_bf16_f32 when available
__device__ __forceinline__ unsigned cvt2(float lo, float hi) {
#if defined(__has_builtin)
#if __has_builtin(__builtin_amdgcn_cvt_pk_bf16_f32)
    typedef __attribute__((ext_vector_type(2))) __bf16 bf16x2_t;
    bf16x2_t t = __builtin_amdgcn_cvt_pk_bf16_f32(lo, hi);
    unsigned u; __builtin_memcpy(&u, &t, 4); return u;
#else
    return ((unsigned)f2bf(hi) << 16) | (unsigned)f2bf(lo);
#endif
#else
    return ((unsigned)f2bf(hi) << 16) | (unsigned)f2bf(lo);
#endif
}

// ---- packed-weight layout offsets in d_ws (u16 units) ----
// B-fragment order: block(kb,nt) = 512 u16, element ((kb*NT+nt)*64 + lane)*8 + j,
// holding W[kb*32 + (lane>>4)*8 + j][nt*16 + (lane&15)]  (zero-padded past Ksrc).
#define SZ_EE1 (1*8*512)
#define SZ_EE2 (4*8*512)
#define SZ_EW1 (12*8*512)
#define SZ_EW2 (4*8*512)
#define SZ_NW1 (8*8*512)
#define SZ_NW2 (4*8*512)
#define SZ_DW1 (4*4*512)
#define OFF_EE1 0
#define OFF_EE2 (OFF_EE1 + SZ_EE1)
#define OFF_EW1 (OFF_EE2 + SZ_EE2)
#define OFF_EW2 (OFF_EW1 + 4*SZ_EW1)
#define OFF_NW1 (OFF_EW2 + 4*SZ_EW2)
#define OFF_NW2 (OFF_NW1 + 4*SZ_NW1)
#define OFF_DW1 (OFF_NW2 + 4*SZ_NW2)

__device__ __forceinline__ void pack_one(const float* __restrict__ s, u16* __restrict__ d,
                                         int Ksrc, int N, int NT, int kbnt) {
    const int kb = kbnt / NT, nt = kbnt % NT;
    const int ln = threadIdx.x, q = ln >> 4, c = ln & 15;
    const int n  = nt * 16 + c;
    u16* dp = d + ((kb * NT + nt) * 64 + ln) * 8;
#pragma unroll
    for (int j = 0; j < 8; ++j) {
        int k = kb * 32 + q * 8 + j;
        dp[j] = f2bf((k < Ksrc) ? s[k * N + n] : 0.f);
    }
}

// Single merged pack kernel: grid.x = 952 blocks x 64 threads.
__global__ void pack_all(const float* __restrict__ ee1, const float* __restrict__ ee2,
                         const float* __restrict__ ew1, const float* __restrict__ ew2,
                         const float* __restrict__ nw1, const float* __restrict__ nw2,
                         const float* __restrict__ dw1, u16* __restrict__ ws) {
    int b = blockIdx.x;
    if (b < 8)        { pack_one(ee1, ws + OFF_EE1, 6, 128, 8, b); return; }
    b -= 8;
    if (b < 32)       { pack_one(ee2, ws + OFF_EE2, 128, 128, 8, b); return; }
    b -= 32;
    if (b < 384)      { int l = b / 96;
                        pack_one(ew1 + l*384*128, ws + OFF_EW1 + l*SZ_EW1, 384, 128, 8, b % 96); return; }
    b -= 384;
    if (b < 128)      { int l = b / 32;
                        pack_one(ew2 + l*128*128, ws + OFF_EW2 + l*SZ_EW2, 128, 128, 8, b % 32); return; }
    b -= 128;
    if (b < 256)      { int l = b / 64;
                        pack_one(nw1 + l*256*128, ws + OFF_NW1 + l*SZ_NW1, 256, 128, 8, b % 64); return; }
    b -= 256;
    if (b < 128)      { int l = b / 32;
                        pack_one(nw2 + l*128*128, ws + OFF_NW2 + l*SZ_NW2, 128, 128, 8, b % 32); return; }
    b -= 128;
    pack_one(dw1, ws + OFF_DW1, 128, 64, 4, b);
}

// Wave-level GEMM with B-fragment register double-buffer: prefetch kb+1's B
// before issuing kb's MFMA group, so the L2 load latency overlaps the matrix pipe.
template<int NMT, int NKB, int NT, typename FA>
__device__ __forceinline__ void wave_gemm(const u16* __restrict__ Wp, int nt, int ln,
                                          FA fa, f32x4* acc) {
    const u16* wp = Wp + (nt * 64 + ln) * 8;
    bf16x8 bc = *(const bf16x8*)(wp);
#pragma unroll
    for (int kb = 0; kb < NKB; ++kb) {
        bf16x8 bn;
        if (kb + 1 < NKB) bn = *(const bf16x8*)(wp + (kb + 1) * NT * 512);
#pragma unroll
        for (int mt = 0; mt < NMT; ++mt) {
            bf16x8 a = fa(mt, kb);
            acc[mt] = __builtin_amdgcn_mfma_f32_16x16x32_bf16(a, bc, acc[mt], 0, 0, 0);
        }
        if (kb + 1 < NKB) bc = bn;
    }
}

// acc init = broadcast bias (saves the per-row bias add in the epilogue)
#define BACC(A, N, b) do { _Pragma("unroll") for (int _i = 0; _i < (N); ++_i) \
                           (A)[_i] = (f32x4){(b), (b), (b), (b)}; } while (0)

// One block (512 thr = 8 waves) per graph. bf16 activation mirrors in LDS (~48 KB);
// fp32 residual masters (h_e, h_n) in registers with fixed tile ownership
// (wave wv owns cols wv*16..wv*16+15). MFMA C/D: col=lane&15, row=(lane>>4)*4+reg.
extern "C" __global__ void __launch_bounds__(512, 2)
gnn_mfma(const float* __restrict__ x_nodes, const float* __restrict__ damage_locs,
         const float* __restrict__ enc_n_w, const float* __restrict__ enc_n_b,
         const float* __restrict__ enc_e_b1, const float* __restrict__ enc_e_b2,
         const float* __restrict__ edge_b1, const float* __restrict__ edge_b2,
         const float* __restrict__ node_b1, const float* __restrict__ node_b2,
         const float* __restrict__ dec_b1, const float* __restrict__ dec_w2,
         const float* __restrict__ dec_b2,
         const u16* __restrict__ wpack, float* __restrict__ out)
{
    __shared__ __align__(16) u16 smem[176 * ST];
    __shared__ float s_x[NSENS * 2];
    __shared__ float s_dmg[2];
    __shared__ float s_val[NEDGE];
    __shared__ int s_src[NEDGE], s_dst[NEDGE];

    u16* b_he  = smem;               // 80*ST  edge features (bf16 mirror)
    u16* b_t   = smem + 80 * ST;     // 80*ST  MLP hidden
    u16* b_hn  = smem + 160 * ST;    // 16*ST  node features
    u16* b_ph  = b_he;               // alias: phys dead once EE1 consumed it
    u16* b_nin = b_t;                // alias: [h_n|agg] 16 x STNIN = 4224 u16 (< 48*ST)
    u16* b_nt  = b_t + 48 * ST;      // alias: node hidden, rows 48-63 of b_t region

    const int g   = blockIdx.x;
    const int tid = threadIdx.x;
    const int wv  = tid >> 6, ln = tid & 63;
    const int q   = ln >> 4,  cl = ln & 15;
    const int col = wv * 16 + cl;          // this wave's output column (128-wide GEMMs)

    // 4-row column store, rows Rb..Rb+3 at fixed col (C-fragment -> bf16 mirror)
    auto st4 = [&](u16* buf, int stride, int c, int Rb, int Rlim,
                   float v0, float v1, float v2, float v3) {
        unsigned d01 = cvt2(v0, v1), d23 = cvt2(v2, v3);
        if (Rb + 0 < Rlim) buf[(Rb + 0) * stride + c] = (u16)d01;
        if (Rb + 1 < Rlim) buf[(Rb + 1) * stride + c] = (u16)(d01 >> 16);
        if (Rb + 2 < Rlim) buf[(Rb + 2) * stride + c] = (u16)d23;
        if (Rb + 3 < Rlim) buf[(Rb + 3) * stride + c] = (u16)(d23 >> 16);
    };

    // ---- zero ONLY the phys region (its K-pad cols multiply zeroed W rows, but
    // NaN*0=NaN, so they must be finite-zero). All other pad rows feed discarded
    // C-rows only (MFMA A-row garbage cannot cross rows). ----
    {
        uint4 z = {0, 0, 0, 0};
        uint4* zp = (uint4*)b_ph;
        for (int i = tid; i < (80 * STPH * 2) / 16; i += 512) zp[i] = z;
    }
    if (tid < NSENS * 2) s_x[tid] = x_nodes[g * NSENS * 2 + tid];
    if (tid < 2)         s_dmg[tid] = damage_locs[g * 2 + tid];
    if (tid < NEDGE) {
        int p = tid >> 1;
        int i = 0, rem = p, cnt = 8;
        while (rem >= cnt) { rem -= cnt; --cnt; ++i; }
        int j = i + 1 + rem;
        s_src[tid] = (tid & 1) ? j : i;
        s_dst[tid] = (tid & 1) ? i : j;
    }
    __syncthreads();

    // ---- phys features -> b_ph (rows<72, cols 0..5 of 32) ----
    if (tid < NEDGE) {
        const int si = s_src[tid], di = s_dst[tid];
        const float sx = s_x[2*si], sy = s_x[2*si+1];
        const float dx = s_x[2*di], dy = s_x[2*di+1];
        const float gx = s_dmg[0],  gy = s_dmg[1];
        const float vx = sx - dx, vy = sy - dy;
        const float vv = vx*vx + vy*vy;
        const float elen = sqrtf(vv + FEPS);
        const float l2 = fmaxf(vv, FEPS);
        float t = ((gx - sx) * (dx - sx) + (gy - sy) * (dy - sy)) / l2;
        t = fminf(fmaxf(t, 0.f), 1.f);
        const float px = sx + t * (dx - sx), py = sy + t * (dy - sy);
        u16* ph = b_ph + tid * STPH;
        ph[0] = f2bf(vx); ph[1] = f2bf(vy); ph[2] = f2bf(elen);
        ph[3] = f2bf(sqrtf((gx-px)*(gx-px) + (gy-py)*(gy-py) + FEPS));
        ph[4] = f2bf(sqrtf((sx-gx)*(sx-gx) + (sy-gy)*(sy-gy) + FEPS));
        ph[5] = f2bf(sqrtf((dx-gx)*(dx-gx) + (dy-gy)*(dy-gy) + FEPS));
    }

    // ---- node encoder (K=2) -> fp32 master m_hn + bf16 mirror ----
    f32x4 m_hn;
    {
        const float w0 = enc_n_w[col], w1 = enc_n_w[HDIM + col], bb = enc_n_b[col];
#pragma unroll
        for (int r = 0; r < 4; ++r) {
            const int R = q * 4 + r;
            m_hn[r] = (R < NSENS) ? fmaf(s_x[2*R], w0, fmaf(s_x[2*R+1], w1, bb)) : 0.f;
        }
        st4(b_hn, ST, col, q * 4, NSENS, m_hn[0], m_hn[1], m_hn[2], m_hn[3]);
    }

    // per-lane edge-row indirection offsets (constant across layers)
    int rowS[5], rowD[5], rowE[5];
#pragma unroll
    for (int mt = 0; mt < 5; ++mt) {
        int e = mt * 16 + cl; if (e >= NEDGE) e = NEDGE - 1;
        rowS[mt] = s_src[e] * ST; rowD[mt] = s_dst[e] * ST; rowE[mt] = e * ST;
    }
    __syncthreads();

    auto fa_t   = [&](int mt, int kb) -> bf16x8 {
        return *(const bf16x8*)(b_t + (mt * 16 + cl) * ST + kb * 32 + q * 8); };
    auto fa_ph  = [&](int mt, int kb) -> bf16x8 {
        return *(const bf16x8*)(b_ph + (mt * 16 + cl) * STPH + q * 8); };
    auto fa_nin = [&](int mt, int kb) -> bf16x8 {
        return *(const bf16x8*)(b_nin + cl * STNIN + kb * 32 + q * 8); };
    auto fa_nt  = [&](int mt, int kb) -> bf16x8 {
        return *(const bf16x8*)(b_nt + cl * ST + kb * 32 + q * 8); };
    auto fa_ein = [&](int mt, int kb) -> bf16x8 {
        const u16* p;
        if (kb < 4)      p = b_hn + rowS[mt] + kb * 32;
        else if (kb < 8) p = b_hn + rowD[mt] + (kb - 4) * 32;
        else             p = b_he + rowE[mt] + (kb - 8) * 32;
        return *(const bf16x8*)(p + q * 8); };

    f32x4 m_he[5];

    // ---- edge encoder GEMM1: relu(phys @ W1 + b1) -> b_t ----
    {
        f32x4 acc[5]; BACC(acc, 5, enc_e_b1[col]);
        wave_gemm<5, 1, 8>(wpack + OFF_EE1, wv, ln, fa_ph, acc);
#pragma unroll
        for (int mt = 0; mt < 5; ++mt)
            st4(b_t, ST, col, mt * 16 + q * 4, NEDGE,
                fmaxf(acc[mt][0], 0.f), fmaxf(acc[mt][1], 0.f),
                fmaxf(acc[mt][2], 0.f), fmaxf(acc[mt][3], 0.f));
    }
    __syncthreads();
    // ---- edge encoder GEMM2 -> m_he (init), b_he (overwrites phys region) ----
    {
        f32x4 acc[5]; BACC(acc, 5, enc_e_b2[col]);
        wave_gemm<5, 4, 8>(wpack + OFF_EE2, wv, ln, fa_t, acc);
#pragma unroll
        for (int mt = 0; mt < 5; ++mt) {
            m_he[mt] = acc[mt];
            st4(b_he, ST, col, mt * 16 + q * 4, NEDGE,
                m_he[mt][0], m_he[mt][1], m_he[mt][2], m_he[mt][3]);
        }
    }
    __syncthreads();

    // ---- message-passing layers ----
    for (int l = 0; l < NLAYER; ++l) {
        // edge MLP1: relu([h_src|h_dst|h_e] @ W1 + b1) -> b_t
        {
            f32x4 acc[5]; BACC(acc, 5, edge_b1[l * HDIM + col]);
            wave_gemm<5, 12, 8>(wpack + OFF_EW1 + l * SZ_EW1, wv, ln, fa_ein, acc);
#pragma unroll
            for (int mt = 0; mt < 5; ++mt)
                st4(b_t, ST, col, mt * 16 + q * 4, NEDGE,
                    fmaxf(acc[mt][0], 0.f), fmaxf(acc[mt][1], 0.f),
                    fmaxf(acc[mt][2], 0.f), fmaxf(acc[mt][3], 0.f));
        }
        __syncthreads();
        // edge MLP2: h_e += hidden @ W2 + b2 (fp32 master), refresh bf16 mirror
        {
            f32x4 acc[5]; BACC(acc, 5, edge_b2[l * HDIM + col]);
            wave_gemm<5, 4, 8>(wpack + OFF_EW2 + l * SZ_EW2, wv, ln, fa_t, acc);
#pragma unroll
            for (int mt = 0; mt < 5; ++mt) {
#pragma unroll
                for (int r = 0; r < 4; ++r) m_he[mt][r] += acc[mt][r];
                st4(b_he, ST, col, mt * 16 + q * 4, NEDGE,
                    m_he[mt][0], m_he[mt][1], m_he[mt][2], m_he[mt][3]);
            }
        }
        __syncthreads();
        // node agg: colsum via cross-lane; b_nin = [h_n | (sum-h)/8] (aliases b_t)
        {
            float p4 = m_hn[0] + m_hn[1] + m_hn[2] + m_hn[3]; // pad rows are 0 in regs
            p4 += __shfl_xor(p4, 16);
            p4 += __shfl_xor(p4, 32);
            st4(b_nin, STNIN, col, q * 4, NSENS, m_hn[0], m_hn[1], m_hn[2], m_hn[3]);
            st4(b_nin, STNIN, HDIM + col, q * 4, NSENS,
                (p4 - m_hn[0]) * 0.125f, (p4 - m_hn[1]) * 0.125f,
                (p4 - m_hn[2]) * 0.125f, (p4 - m_hn[3]) * 0.125f);
        }
        __syncthreads();
        // node MLP1 -> b_nt
        {
            f32x4 acc[1]; BACC(acc, 1, node_b1[l * HDIM + col]);
            wave_gemm<1, 8, 8>(wpack + OFF_NW1 + l * SZ_NW1, wv, ln, fa_nin, acc);
            st4(b_nt, ST, col, q * 4, 16,
                fmaxf(acc[0][0], 0.f), fmaxf(acc[0][1], 0.f),
                fmaxf(acc[0][2], 0.f), fmaxf(acc[0][3], 0.f));
        }
        __syncthreads();
        // node MLP2: h_n += hidden @ W2 + b2, refresh bf16 mirror (rows<9 only)
        {
            f32x4 acc[1]; BACC(acc, 1, node_b2[l * HDIM + col]);
            wave_gemm<1, 4, 8>(wpack + OFF_NW2 + l * SZ_NW2, wv, ln, fa_nt, acc);
#pragma unroll
            for (int r = 0; r < 4; ++r)
                if (q * 4 + r < NSENS) m_hn[r] += acc[0][r];
            st4(b_hn, ST, col, q * 4, NSENS, m_hn[0], m_hn[1], m_hn[2], m_hn[3]);
        }
        __syncthreads();
    }

    // ---- decoder GEMM1 (N=64): relu(h_e @ dec_w1 + b1) -> b_t cols 0..63 ----
    {
        const int ntd = wv & 3;
        const int mt0 = (wv < 4) ? 0 : 2;     // waves 0-3: mt 0-2; waves 4-7: mt 2-4
        auto fa_d = [&](int mt, int kb) -> bf16x8 {
            return *(const bf16x8*)(b_he + ((mt0 + mt) * 16 + cl) * ST + kb * 32 + q * 8); };
        const int c64 = ntd * 16 + cl;
        f32x4 acc[3]; BACC(acc, 3, dec_b1[c64]);  // (mt=2 computed twice -> same-value race, benign)
        wave_gemm<3, 4, 4>(wpack + OFF_DW1, ntd, ln, fa_d, acc);
#pragma unroll
        for (int mt = 0; mt < 3; ++mt)
            st4(b_t, ST, c64, (mt0 + mt) * 16 + q * 4, NEDGE,
                fmaxf(acc[mt][0], 0.f), fmaxf(acc[mt][1], 0.f),
                fmaxf(acc[mt][2], 0.f), fmaxf(acc[mt][3], 0.f));
    }
    __syncthreads();
    // ---- decoder GEMM2 (N=1) + sigmoid ----
    if (tid < NEDGE) {
        float a = dec_b2[0];
        const u16* tt = b_t + tid * ST;
#pragma unroll
        for (int k = 0; k < 64; ++k) a = fmaf(bf2f(tt[k]), dec_w2[k], a);
        s_val[tid] = 1.f / (1.f + expf(-a));
    }
    __syncthreads();
    if (tid < NPAIR)
        out[g * NPAIR + tid] = 0.5f * (s_val[2 * tid] + s_val[2 * tid + 1]);
}

extern "C" void kernel_launch(void* const* d_in, const int* in_sizes, int n_in,
                              void* d_out, int out_size, void* d_ws, size_t ws_size,
                              hipStream_t stream) {
    const float* x_nodes     = (const float*)d_in[0];
    const float* damage_locs = (const float*)d_in[1];
    const float* enc_n_w  = (const float*)d_in[2];
    const float* enc_n_b  = (const float*)d_in[3];
    const float* enc_e_w1 = (const float*)d_in[4];
    const float* enc_e_b1 = (const float*)d_in[5];
    const float* enc_e_w2 = (const float*)d_in[6];
    const float* enc_e_b2 = (const float*)d_in[7];
    const float* edge_w1  = (const float*)d_in[8];
    const float* edge_b1  = (const float*)d_in[9];
    const float* edge_w2  = (const float*)d_in[10];
    const float* edge_b2  = (const float*)d_in[11];
    const float* node_w1  = (const float*)d_in[12];
    const float* node_b1  = (const float*)d_in[13];
    const float* node_w2  = (const float*)d_in[14];
    const float* node_b2  = (const float*)d_in[15];
    const float* dec_w1   = (const float*)d_in[16];
    const float* dec_b1   = (const float*)d_in[17];
    const float* dec_w2   = (const float*)d_in[18];
    const float* dec_b2   = (const float*)d_in[19];
    float* out = (float*)d_out;
    u16* ws = (u16*)d_ws;

    // single merged pack launch (bf16, B-fragment order)
    hipLaunchKernelGGL(pack_all, dim3(952), dim3(64), 0, stream,
                       enc_e_w1, enc_e_w2, edge_w1, edge_w2, node_w1, node_w2, dec_w1, ws);

    const int ngraph = in_sizes[1] / 2;   // damage_locs is [B,2]
    hipLaunchKernelGGL(gnn_mfma, dim3(ngraph), dim3(512), 0, stream,
                       x_nodes, damage_locs, enc_n_w, enc_n_b,
                       enc_e_b1, enc_e_b2, edge_b1, edge_b2,
                       node_b1, node_b2, dec_b1, dec_w2, dec_b2,
                       ws, out);
}